// Round 1
// baseline (1091.197 us; speedup 1.0000x reference)
//
#include <hip/hip_runtime.h>
#include <hip/hip_bf16.h>

// MoE (img/txt mixture) transformer block for MI355X.
// Round 0: correctness-first full pipeline, bf16 MFMA GEMMs (m97-style
// 128x128 tile, BK=64, global_load_lds width-16 staging), flash attention
// with softcap (no online max needed: logits bounded by +-50).
// Requires ws_size >= ~281 MB.

typedef __hip_bfloat16 bf16;
typedef __attribute__((ext_vector_type(8))) __bf16 bf16x8;
typedef __attribute__((ext_vector_type(4))) float f32x4;

#define DEV __device__ __forceinline__

static constexpr int TT = 1536;          // total tokens per batch (1024 img + 512 txt)
static constexpr int NHQ = 16, NKVH = 8, HDM = 128;

DEV void async_load16(const void* g, void* l) {
  typedef const __attribute__((address_space(1))) void* gas_t;
  typedef __attribute__((address_space(3))) void* las_t;
  __builtin_amdgcn_global_load_lds((gas_t)g, (las_t)l, 16, 0, 0);
}

DEV f32x4 mfma16(bf16x8 a, bf16x8 b, f32x4 c) {
  return __builtin_amdgcn_mfma_f32_16x16x32_bf16(a, b, c, 0, 0, 0);
}

DEV float bf2f(bf16 x) { return __bfloat162float(x); }
DEV bf16  f2bf(float x) { return __float2bfloat16(x); }

// ---------------------------------------------------------------------------
// Weight transpose+convert: f32 [K][N] -> bf16 [N][K]
// ---------------------------------------------------------------------------
struct TJob { const float* src; bf16* dst; int K; int N; };
struct TJobs { TJob j[14]; int cum[15]; };

__global__ __launch_bounds__(256) void wt_transpose(TJobs P) {
  __shared__ bf16 tile[64][65];
  int bid = blockIdx.x;
  int ji = 0;
  while (ji < 13 && bid >= P.cum[ji + 1]) ji++;
  const TJob jb = P.j[ji];
  int rel = bid - P.cum[ji];
  int ntc = jb.N >> 6;
  int tr = rel / ntc, tc = rel - tr * ntc;
  int r0 = tr << 6, c0 = tc << 6;
  int t = threadIdx.x;
  #pragma unroll
  for (int i = 0; i < 16; i++) {
    int idx = i * 256 + t;
    int r = idx >> 6, c = idx & 63;
    tile[c][r] = f2bf(jb.src[(size_t)(r0 + r) * jb.N + c0 + c]);
  }
  __syncthreads();
  #pragma unroll
  for (int i = 0; i < 16; i++) {
    int idx = i * 256 + t;
    int r = idx >> 6, c = idx & 63;
    jb.dst[(size_t)(c0 + r) * jb.K + r0 + c] = tile[r][c];
  }
}

// bf16 transpose for V: v_all [B*TT][NKVH*HDM] -> vt [B*NKVH][HDM][TT]
__global__ __launch_bounds__(256) void transpose_v(const bf16* __restrict__ v_all,
                                                   bf16* __restrict__ vt) {
  int st = blockIdx.x, ht = blockIdx.y, bk = blockIdx.z;
  int b = bk >> 3, kv = bk & 7;
  __shared__ bf16 tile[64][65];
  int t = threadIdx.x;
  int s0 = st * 64, h0 = ht * 64;
  #pragma unroll
  for (int i = 0; i < 16; i++) {
    int idx = i * 256 + t;
    int r = idx >> 6, c = idx & 63;  // r: s, c: h
    tile[c][r] = v_all[((size_t)(b * TT + s0 + r) * NKVH + kv) * HDM + h0 + c];
  }
  __syncthreads();
  #pragma unroll
  for (int i = 0; i < 16; i++) {
    int idx = i * 256 + t;
    int r = idx >> 6, c = idx & 63;  // r: h, c: s
    vt[((size_t)bk * HDM + h0 + r) * TT + s0 + c] = tile[r][c];
  }
}

// ---------------------------------------------------------------------------
// RMSNorm: f32 [rows][D] -> bf16, out = x * rsqrt(mean(x^2)+eps) * (1+scale)
// ---------------------------------------------------------------------------
template <int DV>  // D = DV*1024
__global__ __launch_bounds__(256) void rmsnorm_k(const float* __restrict__ x,
                                                 const float* __restrict__ sc,
                                                 bf16* __restrict__ out) {
  const int D = DV * 1024;
  int row = blockIdx.x, t = threadIdx.x;
  const float4* xr = reinterpret_cast<const float4*>(x + (size_t)row * D);
  float4 v[DV];
  float ss = 0.f;
  #pragma unroll
  for (int i = 0; i < DV; i++) {
    v[i] = xr[t + i * 256];
    ss += v[i].x * v[i].x + v[i].y * v[i].y + v[i].z * v[i].z + v[i].w * v[i].w;
  }
  #pragma unroll
  for (int o = 1; o < 64; o <<= 1) ss += __shfl_xor(ss, o);
  __shared__ float red[4];
  if ((t & 63) == 0) red[t >> 6] = ss;
  __syncthreads();
  float r = rsqrtf((red[0] + red[1] + red[2] + red[3]) * (1.0f / D) + 1e-6f);
  bf16* orow = out + (size_t)row * D;
  #pragma unroll
  for (int i = 0; i < DV; i++) {
    int c = (t + i * 256) * 4;
    orow[c + 0] = f2bf(v[i].x * r * (1.f + sc[c + 0]));
    orow[c + 1] = f2bf(v[i].y * r * (1.f + sc[c + 1]));
    orow[c + 2] = f2bf(v[i].z * r * (1.f + sc[c + 2]));
    orow[c + 3] = f2bf(v[i].w * r * (1.f + sc[c + 3]));
  }
}

// ---------------------------------------------------------------------------
// RoPE in-place on [B*TT][nheads][128] bf16; pos = row index within TT.
// scale applied after rotation (HD^-0.5 for q, 1 for k).
// ---------------------------------------------------------------------------
__global__ __launch_bounds__(256) void rope_inplace(bf16* __restrict__ x, int lognh,
                                                    float scale) {
  int gid = blockIdx.x * 256 + threadIdx.x;
  int i = gid & 63;
  int rh = gid >> 6;
  int row = rh >> lognh;
  int pos = row >= TT ? row - TT : row;
  float fr = expf(-9.210340371976184f * ((float)(2 * i) * (1.0f / 128.0f)));
  float th = (float)pos * fr;
  float s, c;
  sincosf(th, &s, &c);
  bf16* p = x + (size_t)rh * HDM;
  float x1 = bf2f(p[i]), x2 = bf2f(p[i + 64]);
  p[i]      = f2bf((x1 * c - x2 * s) * scale);
  p[i + 64] = f2bf((x2 * c + x1 * s) * scale);
}

// ---------------------------------------------------------------------------
// GEMM core: C[128x128] += A[128xK] * B^T[128xK]^T, m97-style.
// A row remap: phys_row = a_base + m + ((m>>a_lsh)*a_lskip)
// ---------------------------------------------------------------------------
template <bool DUALB>
DEV void gemm_core(const bf16* __restrict__ A, int K, int a_base, int a_lsh,
                   int a_lskip, const bf16* __restrict__ B0,
                   const bf16* __restrict__ B1, int m0, bf16* As, bf16* Bs,
                   bf16* Bs1, f32x4 acc[4][4], f32x4 acc2[4][4]) {
  const int tid = threadIdx.x, w = tid >> 6, l = tid & 63;
  const int lr = l & 15, lk = l >> 4;
  const int wm = (w >> 1) * 64, wn = (w & 1) * 64;
  for (int k0 = 0; k0 < K; k0 += 64) {
    __syncthreads();
    #pragma unroll
    for (int i = 0; i < 4; i++) {
      int cb = (w * 4 + i) * 64;
      int c = cb + l;
      int row = c >> 3, c8 = c & 7;
      int m = m0 + row;
      int pr = a_base + m + ((m >> a_lsh) * a_lskip);
      async_load16(A + (size_t)pr * K + k0 + c8 * 8, As + cb * 8);
      async_load16(B0 + (size_t)row * K + k0 + c8 * 8, Bs + cb * 8);
      if (DUALB) async_load16(B1 + (size_t)row * K + k0 + c8 * 8, Bs1 + cb * 8);
    }
    __syncthreads();
    #pragma unroll
    for (int kk = 0; kk < 2; kk++) {
      bf16x8 af[4], bfr[4], b2[4];
      #pragma unroll
      for (int mi = 0; mi < 4; mi++)
        af[mi] = *reinterpret_cast<const bf16x8*>(As + (wm + mi * 16 + lr) * 64 + kk * 32 + lk * 8);
      #pragma unroll
      for (int ni = 0; ni < 4; ni++)
        bfr[ni] = *reinterpret_cast<const bf16x8*>(Bs + (wn + ni * 16 + lr) * 64 + kk * 32 + lk * 8);
      if (DUALB) {
        #pragma unroll
        for (int ni = 0; ni < 4; ni++)
          b2[ni] = *reinterpret_cast<const bf16x8*>(Bs1 + (wn + ni * 16 + lr) * 64 + kk * 32 + lk * 8);
      }
      #pragma unroll
      for (int mi = 0; mi < 4; mi++)
        #pragma unroll
        for (int ni = 0; ni < 4; ni++) {
          acc[mi][ni] = mfma16(af[mi], bfr[ni], acc[mi][ni]);
          if (DUALB) acc2[mi][ni] = mfma16(af[mi], b2[ni], acc2[mi][ni]);
        }
    }
  }
}

DEV void zero_acc(f32x4 a[4][4]) {
  #pragma unroll
  for (int i = 0; i < 4; i++)
    #pragma unroll
    for (int j = 0; j < 4; j++) a[i][j] = (f32x4){0.f, 0.f, 0.f, 0.f};
}

// QKV fused GEMM: N = 4096 split as q[0,2048) k[2048,3072) v[3072,4096).
// C row remap: crow = c_base + m + ((m>>c_lsh)*c_lskip)  (concat-seq rows)
__global__ __launch_bounds__(256) void gemm_qkv(
    const bf16* __restrict__ A, int K, const bf16* __restrict__ WqT,
    const bf16* __restrict__ WkT, const bf16* __restrict__ WvT,
    bf16* __restrict__ q_all, bf16* __restrict__ k_all, bf16* __restrict__ v_all,
    int c_base, int c_lsh, int c_lskip) {
  __shared__ __align__(16) bf16 smem[2 * 128 * 64];
  int m0 = blockIdx.x * 128, n0 = blockIdx.y * 128;
  const bf16* Bp;
  bf16* dst;
  int dstr, nrel;
  if (n0 < NHQ * HDM) {
    Bp = WqT + (size_t)n0 * K; dst = q_all; dstr = NHQ * HDM; nrel = n0;
  } else if (n0 < (NHQ + NKVH) * HDM) {
    int r = n0 - NHQ * HDM;
    Bp = WkT + (size_t)r * K; dst = k_all; dstr = NKVH * HDM; nrel = r;
  } else {
    int r = n0 - (NHQ + NKVH) * HDM;
    Bp = WvT + (size_t)r * K; dst = v_all; dstr = NKVH * HDM; nrel = r;
  }
  f32x4 acc[4][4];
  zero_acc(acc);
  gemm_core<false>(A, K, 0, 30, 0, Bp, nullptr, m0, smem, smem + 128 * 64,
                   nullptr, acc, acc);
  const int l = threadIdx.x & 63, w = threadIdx.x >> 6;
  const int lr = l & 15, lk = l >> 4, wm = (w >> 1) * 64, wn = (w & 1) * 64;
  #pragma unroll
  for (int mi = 0; mi < 4; mi++)
    #pragma unroll
    for (int j = 0; j < 4; j++) {
      int m = m0 + wm + mi * 16 + lk * 4 + j;
      int crow = c_base + m + ((m >> c_lsh) * c_lskip);
      bf16* drow = dst + (size_t)crow * dstr + nrel + wn;
      #pragma unroll
      for (int ni = 0; ni < 4; ni++) drow[ni * 16 + lr] = f2bf(acc[mi][ni][j]);
    }
}

// GEMM + f32 residual add -> f32 out (used for WO->h and DOWN->d_out)
__global__ __launch_bounds__(256) void gemm_resid(
    const bf16* __restrict__ A, int K, int a_base, int a_lsh, int a_lskip,
    const bf16* __restrict__ BT, const float* __restrict__ resid,
    float* __restrict__ out, int N) {
  __shared__ __align__(16) bf16 smem[2 * 128 * 64];
  int m0 = blockIdx.x * 128, n0 = blockIdx.y * 128;
  f32x4 acc[4][4];
  zero_acc(acc);
  gemm_core<false>(A, K, a_base, a_lsh, a_lskip, BT + (size_t)n0 * K, nullptr,
                   m0, smem, smem + 128 * 64, nullptr, acc, acc);
  const int l = threadIdx.x & 63, w = threadIdx.x >> 6;
  const int lr = l & 15, lk = l >> 4, wm = (w >> 1) * 64, wn = (w & 1) * 64;
  #pragma unroll
  for (int mi = 0; mi < 4; mi++)
    #pragma unroll
    for (int j = 0; j < 4; j++) {
      int m = m0 + wm + mi * 16 + lk * 4 + j;
      size_t ro = (size_t)m * N + n0 + wn;
      #pragma unroll
      for (int ni = 0; ni < 4; ni++) {
        int cc = ni * 16 + lr;
        out[ro + cc] = acc[mi][ni][j] + resid[ro + cc];
      }
    }
}

// gate+up dual GEMM with fused GELU(g)*u -> bf16 act
__global__ __launch_bounds__(256) void gemm_gateup(
    const bf16* __restrict__ A, int K, const bf16* __restrict__ WgT,
    const bf16* __restrict__ WuT, bf16* __restrict__ act, int N) {
  __shared__ __align__(16) bf16 smem[3 * 128 * 64];
  int m0 = blockIdx.x * 128, n0 = blockIdx.y * 128;
  f32x4 acc[4][4], acc2[4][4];
  zero_acc(acc);
  zero_acc(acc2);
  gemm_core<true>(A, K, 0, 30, 0, WgT + (size_t)n0 * K, WuT + (size_t)n0 * K,
                  m0, smem, smem + 128 * 64, smem + 2 * 128 * 64, acc, acc2);
  const int l = threadIdx.x & 63, w = threadIdx.x >> 6;
  const int lr = l & 15, lk = l >> 4, wm = (w >> 1) * 64, wn = (w & 1) * 64;
  #pragma unroll
  for (int mi = 0; mi < 4; mi++)
    #pragma unroll
    for (int j = 0; j < 4; j++) {
      int m = m0 + wm + mi * 16 + lk * 4 + j;
      size_t ro = (size_t)m * N + n0 + wn;
      #pragma unroll
      for (int ni = 0; ni < 4; ni++) {
        float g = acc[mi][ni][j], u = acc2[mi][ni][j];
        float t = tanhf(0.7978845608028654f * (g + 0.044715f * g * g * g));
        act[ro + ni * 16 + lr] = f2bf(0.5f * g * (1.f + t) * u);
      }
    }
}

// ---------------------------------------------------------------------------
// Flash attention with softcap (no online max; logits bounded by +-50).
// q_all [B*TT][NHQ][HDM], k_all [B*TT][NKVH][HDM], vt [B*NKVH][HDM][TT]
// out attn_o [B*TT][NHQ*HDM] bf16. Head n uses kv head n>>1.
// ---------------------------------------------------------------------------
__global__ __launch_bounds__(256) void attn_k(const bf16* __restrict__ q_all,
                                              const bf16* __restrict__ k_all,
                                              const bf16* __restrict__ vt,
                                              bf16* __restrict__ attn_o) {
  const int qt = blockIdx.x;  // 24 q-tiles of 64
  const int n = blockIdx.y;   // head
  const int b = blockIdx.z;
  const int kv = n >> 1;
  const int tid = threadIdx.x, w = tid >> 6, l = tid & 63;
  const int lr = l & 15, lk = l >> 4;
  __shared__ __align__(16) bf16 Ksm[64 * 128];
  __shared__ __align__(16) bf16 Vsm[128 * 64];
  __shared__ __align__(16) bf16 Psm[4][16][72];

  bf16x8 qf[4];
  {
    int t = qt * 64 + w * 16 + lr;
    const bf16* qp = q_all + ((size_t)(b * TT + t) * NHQ + n) * HDM;
    #pragma unroll
    for (int kk = 0; kk < 4; kk++)
      qf[kk] = *reinterpret_cast<const bf16x8*>(qp + kk * 32 + lk * 8);
  }
  f32x4 acc_o[8];
  #pragma unroll
  for (int i = 0; i < 8; i++) acc_o[i] = (f32x4){0.f, 0.f, 0.f, 0.f};
  float den[4] = {0.f, 0.f, 0.f, 0.f};

  for (int st = 0; st < TT / 64; st++) {
    __syncthreads();
    // stage K tile [64 s][128 hd] and V^T tile [128 h][64 s], XOR-swizzled
    #pragma unroll
    for (int i = 0; i < 4; i++) {
      int cb = (w * 4 + i) * 64;
      int c = cb + l;
      {
        int srow = c >> 4, c16 = c & 15;
        const bf16* g = k_all + ((size_t)(b * TT + st * 64 + srow) * NKVH + kv) * HDM +
                        ((c16 ^ (srow & 7)) << 3);
        async_load16(g, Ksm + cb * 8);
      }
      {
        int hrow = c >> 3, c8 = c & 7;
        const bf16* g = vt + ((size_t)(b * NKVH + kv) * HDM + hrow) * TT + st * 64 +
                        ((c8 ^ (hrow & 7)) << 3);
        async_load16(g, Vsm + cb * 8);
      }
    }
    __syncthreads();
    // QK^T + softcap + exp; write P to LDS, accumulate row sums
    #pragma unroll
    for (int sf = 0; sf < 4; sf++) {
      f32x4 s4 = (f32x4){0.f, 0.f, 0.f, 0.f};
      int sl = sf * 16 + lr;
      #pragma unroll
      for (int kk = 0; kk < 4; kk++) {
        int e = kk * 32 + lk * 8;
        bf16x8 kf = *reinterpret_cast<const bf16x8*>(
            Ksm + sl * 128 + ((((e >> 3) ^ (sl & 7))) << 3));
        s4 = mfma16(qf[kk], kf, s4);
      }
      #pragma unroll
      for (int j = 0; j < 4; j++) {
        float xv = s4[j];
        float tcap = tanhf(xv * 0.02f) * 50.f;
        float p = __expf(tcap);
        Psm[w][lk * 4 + j][sf * 16 + lr] = f2bf(p);
        p += __shfl_xor(p, 1);
        p += __shfl_xor(p, 2);
        p += __shfl_xor(p, 4);
        p += __shfl_xor(p, 8);
        den[j] += p;
      }
    }
    // PV
    #pragma unroll
    for (int kk2 = 0; kk2 < 2; kk2++) {
      bf16x8 pa = *reinterpret_cast<const bf16x8*>(&Psm[w][lr][kk2 * 32 + lk * 8]);
      #pragma unroll
      for (int hf = 0; hf < 8; hf++) {
        int h = hf * 16 + lr;
        int e2 = kk2 * 32 + lk * 8;
        bf16x8 vb = *reinterpret_cast<const bf16x8*>(
            Vsm + h * 64 + ((((e2 >> 3) ^ (h & 7))) << 3));
        acc_o[hf] = mfma16(pa, vb, acc_o[hf]);
      }
    }
  }
  // write out: attn_o[(b*TT+t)][n*HDM + h]
  #pragma unroll
  for (int hf = 0; hf < 8; hf++)
    #pragma unroll
    for (int j = 0; j < 4; j++) {
      int t = qt * 64 + w * 16 + lk * 4 + j;
      float val = acc_o[hf][j] / den[j];
      attn_o[((size_t)(b * TT + t)) * (NHQ * HDM) + n * HDM + hf * 16 + lr] = f2bf(val);
    }
}

// ---------------------------------------------------------------------------
extern "C" void kernel_launch(void* const* d_in, const int* in_sizes, int n_in,
                              void* d_out, int out_size, void* d_ws,
                              size_t ws_size, hipStream_t stream) {
  const float* x_img = (const float*)d_in[0];
  const float* x_txt = (const float*)d_in[1];
  // d_in[2] = attn_mask (all True in this problem) -> ignored
  const float* sc_attn_i = (const float*)d_in[3];
  const float* wq_i = (const float*)d_in[4];
  const float* wk_i = (const float*)d_in[5];
  const float* wv_i = (const float*)d_in[6];
  const float* wo_i = (const float*)d_in[7];
  const float* sc_ffw_i = (const float*)d_in[8];
  const float* wg_i = (const float*)d_in[9];
  const float* wu_i = (const float*)d_in[10];
  const float* wd_i = (const float*)d_in[11];
  const float* sc_attn_t = (const float*)d_in[12];
  const float* wq_t = (const float*)d_in[13];
  const float* wk_t = (const float*)d_in[14];
  const float* wv_t = (const float*)d_in[15];
  const float* wo_t = (const float*)d_in[16];
  const float* sc_ffw_t = (const float*)d_in[17];
  const float* wg_t = (const float*)d_in[18];
  const float* wu_t = (const float*)d_in[19];
  const float* wd_t = (const float*)d_in[20];
  float* outp = (float*)d_out;

  char* ws = (char*)d_ws;
  size_t off = 0;
  auto alloc = [&](size_t n) {
    char* p = ws + off;
    off += (n + 255) & ~(size_t)255;
    return p;
  };
  // bf16 transposed weights [N][K]
  bf16* WqT_i = (bf16*)alloc((size_t)2048 * 2048 * 2);
  bf16* WkT_i = (bf16*)alloc((size_t)1024 * 2048 * 2);
  bf16* WvT_i = (bf16*)alloc((size_t)1024 * 2048 * 2);
  bf16* WoT_i = (bf16*)alloc((size_t)2048 * 2048 * 2);
  bf16* WgT_i = (bf16*)alloc((size_t)8192 * 2048 * 2);
  bf16* WuT_i = (bf16*)alloc((size_t)8192 * 2048 * 2);
  bf16* WdT_i = (bf16*)alloc((size_t)2048 * 8192 * 2);
  bf16* WqT_t = (bf16*)alloc((size_t)2048 * 1024 * 2);
  bf16* WkT_t = (bf16*)alloc((size_t)1024 * 1024 * 2);
  bf16* WvT_t = (bf16*)alloc((size_t)1024 * 1024 * 2);
  bf16* WoT_t = (bf16*)alloc((size_t)1024 * 2048 * 2);
  bf16* WgT_t = (bf16*)alloc((size_t)4096 * 1024 * 2);
  bf16* WuT_t = (bf16*)alloc((size_t)4096 * 1024 * 2);
  bf16* WdT_t = (bf16*)alloc((size_t)1024 * 4096 * 2);
  // activations
  bf16* xn_i = (bf16*)alloc((size_t)2048 * 2048 * 2);   // also reused as hn_i
  bf16* xn_t = (bf16*)alloc((size_t)1024 * 1024 * 2);   // also reused as hn_t
  bf16* q_all = (bf16*)alloc((size_t)3072 * 2048 * 2);
  bf16* k_all = (bf16*)alloc((size_t)3072 * 1024 * 2);
  bf16* v_all = (bf16*)alloc((size_t)3072 * 1024 * 2);
  bf16* vtr = (bf16*)alloc((size_t)3072 * 1024 * 2);
  bf16* attn_o = (bf16*)alloc((size_t)3072 * 2048 * 2);
  float* h_i = (float*)alloc((size_t)2048 * 2048 * 4);
  float* h_t = (float*)alloc((size_t)1024 * 1024 * 4);
  bf16* act_i = (bf16*)alloc((size_t)2048 * 8192 * 2);
  bf16* act_t = (bf16*)alloc((size_t)1024 * 4096 * 2);
  (void)ws_size;  // needs ~281 MB

  // 1. weight transpose/convert
  TJobs tj;
  auto setj = [&](int idx, const float* s, bf16* d, int K, int N) {
    tj.j[idx].src = s; tj.j[idx].dst = d; tj.j[idx].K = K; tj.j[idx].N = N;
  };
  setj(0, wq_i, WqT_i, 2048, 2048);
  setj(1, wk_i, WkT_i, 2048, 1024);
  setj(2, wv_i, WvT_i, 2048, 1024);
  setj(3, wo_i, WoT_i, 2048, 2048);
  setj(4, wg_i, WgT_i, 2048, 8192);
  setj(5, wu_i, WuT_i, 2048, 8192);
  setj(6, wd_i, WdT_i, 8192, 2048);
  setj(7, wq_t, WqT_t, 1024, 2048);
  setj(8, wk_t, WkT_t, 1024, 1024);
  setj(9, wv_t, WvT_t, 1024, 1024);
  setj(10, wo_t, WoT_t, 2048, 1024);
  setj(11, wg_t, WgT_t, 1024, 4096);
  setj(12, wu_t, WuT_t, 1024, 4096);
  setj(13, wd_t, WdT_t, 4096, 1024);
  tj.cum[0] = 0;
  for (int i = 0; i < 14; i++)
    tj.cum[i + 1] = tj.cum[i] + (tj.j[i].K >> 6) * (tj.j[i].N >> 6);
  wt_transpose<<<tj.cum[14], 256, 0, stream>>>(tj);

  // 2. pre-attn RMSNorm
  rmsnorm_k<2><<<2048, 256, 0, stream>>>(x_img, sc_attn_i, xn_i);
  rmsnorm_k<1><<<1024, 256, 0, stream>>>(x_txt, sc_attn_t, xn_t);

  // 3. QKV GEMMs (write into concat-seq layout rows b*1536 + t)
  gemm_qkv<<<dim3(16, 32), 256, 0, stream>>>(xn_i, 2048, WqT_i, WkT_i, WvT_i,
                                             q_all, k_all, v_all, 0, 10, 512);
  gemm_qkv<<<dim3(8, 32), 256, 0, stream>>>(xn_t, 1024, WqT_t, WkT_t, WvT_t,
                                            q_all, k_all, v_all, 1024, 9, 1024);

  // 4. RoPE (in-place; q also scaled by HD^-0.5)
  rope_inplace<<<12288, 256, 0, stream>>>(q_all, 4, 0.08838834764831845f);
  rope_inplace<<<6144, 256, 0, stream>>>(k_all, 3, 1.0f);

  // 5. V transpose for PV MFMA operand layout
  transpose_v<<<dim3(24, 2, 16), 256, 0, stream>>>(v_all, vtr);

  // 6. attention
  attn_k<<<dim3(24, 16, 2), 256, 0, stream>>>(q_all, k_all, vtr, attn_o);

  // 7. WO + residual x -> h (f32)
  gemm_resid<<<dim3(16, 16), 256, 0, stream>>>(attn_o, 2048, 0, 10, 512, WoT_i,
                                               x_img, h_i, 2048);
  gemm_resid<<<dim3(8, 8), 256, 0, stream>>>(attn_o, 2048, 1024, 9, 1024, WoT_t,
                                             x_txt, h_t, 1024);

  // 8. pre-FFW RMSNorm (reuse xn buffers)
  rmsnorm_k<2><<<2048, 256, 0, stream>>>(h_i, sc_ffw_i, xn_i);
  rmsnorm_k<1><<<1024, 256, 0, stream>>>(h_t, sc_ffw_t, xn_t);

  // 9. gate/up dual GEMM + fused GELU*up
  gemm_gateup<<<dim3(16, 64), 256, 0, stream>>>(xn_i, 2048, WgT_i, WuT_i, act_i, 8192);
  gemm_gateup<<<dim3(8, 32), 256, 0, stream>>>(xn_t, 1024, WgT_t, WuT_t, act_t, 4096);

  // 10. down GEMM + residual x -> d_out
  gemm_resid<<<dim3(16, 16), 256, 0, stream>>>(act_i, 8192, 0, 30, 0, WdT_i,
                                               x_img, outp, 2048);
  gemm_resid<<<dim3(8, 8), 256, 0, stream>>>(act_t, 4096, 0, 30, 0, WdT_t,
                                             x_txt, outp + (size_t)2 * 1024 * 2048, 1024);
}

// Round 2
// 848.662 us; speedup vs baseline: 1.2858x; 1.2858x over previous
//
#include <hip/hip_runtime.h>
#include <hip/hip_bf16.h>

// MoE (img/txt mixture) transformer block for MI355X.
// Round 1: uniform job-table GEMM (m97 128x128 2-phase core, single acc),
// gate|up concatenated into one N=16384 GEMM + in-place GELU*mul pass,
// img+txt jobs merged per launch for grid occupancy.
// ws usage ~266 MB.

typedef __hip_bfloat16 bf16;
typedef __attribute__((ext_vector_type(8))) __bf16 bf16x8;
typedef __attribute__((ext_vector_type(4))) float f32x4;

#define DEV __device__ __forceinline__

static constexpr int TT = 1536;          // total tokens per batch (1024 img + 512 txt)
static constexpr int NHQ = 16, NKVH = 8, HDM = 128;

DEV void async_load16(const void* g, void* l) {
  typedef const __attribute__((address_space(1))) void* gas_t;
  typedef __attribute__((address_space(3))) void* las_t;
  __builtin_amdgcn_global_load_lds((gas_t)g, (las_t)l, 16, 0, 0);
}

DEV f32x4 mfma16(bf16x8 a, bf16x8 b, f32x4 c) {
  return __builtin_amdgcn_mfma_f32_16x16x32_bf16(a, b, c, 0, 0, 0);
}

DEV float bf2f(bf16 x) { return __bfloat162float(x); }
DEV bf16  f2bf(float x) { return __float2bfloat16(x); }

// ---------------------------------------------------------------------------
// Weight transpose+convert: f32 [K][N] -> bf16 [N][K]
// ---------------------------------------------------------------------------
struct TJob { const float* src; bf16* dst; int K; int N; };
struct TJobs { TJob j[14]; int cum[15]; };

__global__ __launch_bounds__(256) void wt_transpose(TJobs P) {
  __shared__ bf16 tile[64][65];
  int bid = blockIdx.x;
  int ji = 0;
  while (ji < 13 && bid >= P.cum[ji + 1]) ji++;
  const TJob jb = P.j[ji];
  int rel = bid - P.cum[ji];
  int ntc = jb.N >> 6;
  int tr = rel / ntc, tc = rel - tr * ntc;
  int r0 = tr << 6, c0 = tc << 6;
  int t = threadIdx.x;
  #pragma unroll
  for (int i = 0; i < 16; i++) {
    int idx = i * 256 + t;
    int r = idx >> 6, c = idx & 63;
    tile[c][r] = f2bf(jb.src[(size_t)(r0 + r) * jb.N + c0 + c]);
  }
  __syncthreads();
  #pragma unroll
  for (int i = 0; i < 16; i++) {
    int idx = i * 256 + t;
    int r = idx >> 6, c = idx & 63;
    jb.dst[(size_t)(c0 + r) * jb.K + r0 + c] = tile[r][c];
  }
}

// bf16 transpose for V: v_all [B*TT][NKVH*HDM] -> vt [B*NKVH][HDM][TT]
__global__ __launch_bounds__(256) void transpose_v(const bf16* __restrict__ v_all,
                                                   bf16* __restrict__ vt) {
  int st = blockIdx.x, ht = blockIdx.y, bk = blockIdx.z;
  int b = bk >> 3, kv = bk & 7;
  __shared__ bf16 tile[64][65];
  int t = threadIdx.x;
  int s0 = st * 64, h0 = ht * 64;
  #pragma unroll
  for (int i = 0; i < 16; i++) {
    int idx = i * 256 + t;
    int r = idx >> 6, c = idx & 63;  // r: s, c: h
    tile[c][r] = v_all[((size_t)(b * TT + s0 + r) * NKVH + kv) * HDM + h0 + c];
  }
  __syncthreads();
  #pragma unroll
  for (int i = 0; i < 16; i++) {
    int idx = i * 256 + t;
    int r = idx >> 6, c = idx & 63;  // r: h, c: s
    vt[((size_t)bk * HDM + h0 + r) * TT + s0 + c] = tile[r][c];
  }
}

// ---------------------------------------------------------------------------
// RMSNorm: f32 [rows][D] -> bf16, out = x * rsqrt(mean(x^2)+eps) * (1+scale)
// ---------------------------------------------------------------------------
template <int DV>  // D = DV*1024
__global__ __launch_bounds__(256) void rmsnorm_k(const float* __restrict__ x,
                                                 const float* __restrict__ sc,
                                                 bf16* __restrict__ out) {
  const int D = DV * 1024;
  int row = blockIdx.x, t = threadIdx.x;
  const float4* xr = reinterpret_cast<const float4*>(x + (size_t)row * D);
  float4 v[DV];
  float ss = 0.f;
  #pragma unroll
  for (int i = 0; i < DV; i++) {
    v[i] = xr[t + i * 256];
    ss += v[i].x * v[i].x + v[i].y * v[i].y + v[i].z * v[i].z + v[i].w * v[i].w;
  }
  #pragma unroll
  for (int o = 1; o < 64; o <<= 1) ss += __shfl_xor(ss, o);
  __shared__ float red[4];
  if ((t & 63) == 0) red[t >> 6] = ss;
  __syncthreads();
  float r = rsqrtf((red[0] + red[1] + red[2] + red[3]) * (1.0f / D) + 1e-6f);
  bf16* orow = out + (size_t)row * D;
  #pragma unroll
  for (int i = 0; i < DV; i++) {
    int c = (t + i * 256) * 4;
    orow[c + 0] = f2bf(v[i].x * r * (1.f + sc[c + 0]));
    orow[c + 1] = f2bf(v[i].y * r * (1.f + sc[c + 1]));
    orow[c + 2] = f2bf(v[i].z * r * (1.f + sc[c + 2]));
    orow[c + 3] = f2bf(v[i].w * r * (1.f + sc[c + 3]));
  }
}

// ---------------------------------------------------------------------------
// RoPE in-place on [B*TT][nheads][128] bf16; pos = row index within TT.
// ---------------------------------------------------------------------------
__global__ __launch_bounds__(256) void rope_inplace(bf16* __restrict__ x, int lognh,
                                                    float scale) {
  int gid = blockIdx.x * 256 + threadIdx.x;
  int i = gid & 63;
  int rh = gid >> 6;
  int row = rh >> lognh;
  int pos = row >= TT ? row - TT : row;
  float fr = expf(-9.210340371976184f * ((float)(2 * i) * (1.0f / 128.0f)));
  float th = (float)pos * fr;
  float s, c;
  sincosf(th, &s, &c);
  bf16* p = x + (size_t)rh * HDM;
  float x1 = bf2f(p[i]), x2 = bf2f(p[i + 64]);
  p[i]      = f2bf((x1 * c - x2 * s) * scale);
  p[i + 64] = f2bf((x2 * c + x1 * s) * scale);
}

// ---------------------------------------------------------------------------
// Unified job-table GEMM: C[128x128 tile] = A[M x K] * B^T (B stored [N][K]).
// A row remap: phys_row = a_base + m + ((m>>a_lsh)*a_lskip); A row stride lda.
// Output: bf16 (with C row remap) or f32 (+optional resid).
// ---------------------------------------------------------------------------
struct GJob {
  const bf16* A; const bf16* B;
  bf16* Cb; float* Cf; const float* resid;
  int K, N, lda;
  int a_base, a_lsh, a_lskip;
  int c_base, c_lsh, c_lskip;
  int c_stride;
};
struct GJobs { GJob j[6]; int cum[7]; int nj; };

__global__ __launch_bounds__(256) void gemm_uni(GJobs P) {
  __shared__ __align__(16) bf16 As[128 * 64];
  __shared__ __align__(16) bf16 Bs[128 * 64];
  int bid = blockIdx.x;
  int ji = 0;
  while (ji < P.nj - 1 && bid >= P.cum[ji + 1]) ji++;
  const GJob jb = P.j[ji];
  int rel = bid - P.cum[ji];
  int tn = jb.N >> 7;
  int bm = rel / tn, bn = rel - bm * tn;
  int m0 = bm << 7, n0 = bn << 7;
  const bf16* Bp = jb.B + (size_t)n0 * jb.K;

  const int tid = threadIdx.x, w = tid >> 6, l = tid & 63;
  const int lr = l & 15, lk = l >> 4;
  const int wm = (w >> 1) * 64, wn = (w & 1) * 64;

  f32x4 acc[4][4];
  #pragma unroll
  for (int i = 0; i < 4; i++)
    #pragma unroll
    for (int jj = 0; jj < 4; jj++) acc[i][jj] = (f32x4){0.f, 0.f, 0.f, 0.f};

  const int K = jb.K;
  for (int k0 = 0; k0 < K; k0 += 64) {
    __syncthreads();
    #pragma unroll
    for (int i = 0; i < 4; i++) {
      int cb = (w * 4 + i) * 64;
      int c = cb + l;
      int row = c >> 3, c8 = c & 7;
      int m = m0 + row;
      int pr = jb.a_base + m + ((m >> jb.a_lsh) * jb.a_lskip);
      async_load16(jb.A + (size_t)pr * jb.lda + k0 + c8 * 8, As + cb * 8);
      async_load16(Bp + (size_t)row * K + k0 + c8 * 8, Bs + cb * 8);
    }
    __syncthreads();
    #pragma unroll
    for (int kk = 0; kk < 2; kk++) {
      bf16x8 af[4], bfr[4];
      #pragma unroll
      for (int mi = 0; mi < 4; mi++)
        af[mi] = *reinterpret_cast<const bf16x8*>(As + (wm + mi * 16 + lr) * 64 + kk * 32 + lk * 8);
      #pragma unroll
      for (int ni = 0; ni < 4; ni++)
        bfr[ni] = *reinterpret_cast<const bf16x8*>(Bs + (wn + ni * 16 + lr) * 64 + kk * 32 + lk * 8);
      #pragma unroll
      for (int mi = 0; mi < 4; mi++)
        #pragma unroll
        for (int ni = 0; ni < 4; ni++)
          acc[mi][ni] = mfma16(af[mi], bfr[ni], acc[mi][ni]);
    }
  }

  if (jb.Cf) {
    #pragma unroll
    for (int mi = 0; mi < 4; mi++)
      #pragma unroll
      for (int jj = 0; jj < 4; jj++) {
        int m = m0 + wm + mi * 16 + lk * 4 + jj;
        size_t ro = (size_t)m * jb.c_stride + n0 + wn;
        #pragma unroll
        for (int ni = 0; ni < 4; ni++) {
          int cc = ni * 16 + lr;
          float v = acc[mi][ni][jj];
          if (jb.resid) v += jb.resid[ro + cc];
          jb.Cf[ro + cc] = v;
        }
      }
  } else {
    #pragma unroll
    for (int mi = 0; mi < 4; mi++)
      #pragma unroll
      for (int jj = 0; jj < 4; jj++) {
        int m = m0 + wm + mi * 16 + lk * 4 + jj;
        int crow = jb.c_base + m + ((m >> jb.c_lsh) * jb.c_lskip);
        bf16* drow = jb.Cb + (size_t)crow * jb.c_stride + n0 + wn;
        #pragma unroll
        for (int ni = 0; ni < 4; ni++) drow[ni * 16 + lr] = f2bf(acc[mi][ni][jj]);
      }
  }
}

// ---------------------------------------------------------------------------
// In-place GELU(gate)*up over gu buffers: gu [M][2N]; act written to gate half.
// n_img8 = 2048*8192/8 chunks for img, rest txt.
// ---------------------------------------------------------------------------
__global__ __launch_bounds__(256) void gelu_mul(bf16* __restrict__ gu_i,
                                                bf16* __restrict__ gu_t) {
  const int IMG_CH = 2048 * 8192 / 8;      // 2,097,152
  const int TXT_CH = 1024 * 4096 / 8;      // 524,288
  int idx = blockIdx.x * 256 + threadIdx.x;
  int total = IMG_CH + TXT_CH;
  if (idx >= total) return;
  bf16* base;
  int rowlen, half, ci;
  if (idx < IMG_CH) { base = gu_i; half = 8192; ci = idx; }
  else              { base = gu_t; half = 4096; ci = idx - IMG_CH; }
  rowlen = half * 2;
  int perrow = half / 8;
  int m = ci / perrow, n8 = ci - m * perrow;
  bf16* gp = base + (size_t)m * rowlen + n8 * 8;
  bf16* up = gp + half;
  bf16x8 g8 = *reinterpret_cast<const bf16x8*>(gp);
  bf16x8 u8 = *reinterpret_cast<const bf16x8*>(up);
  bf16x8 o8;
  #pragma unroll
  for (int i = 0; i < 8; i++) {
    float g = (float)g8[i], u = (float)u8[i];
    float t = tanhf(0.7978845608028654f * (g + 0.044715f * g * g * g));
    o8[i] = (__bf16)(0.5f * g * (1.f + t) * u);
  }
  *reinterpret_cast<bf16x8*>(gp) = o8;
}

// ---------------------------------------------------------------------------
// Flash attention with softcap (no online max; logits bounded by +-50).
// ---------------------------------------------------------------------------
__global__ __launch_bounds__(256) void attn_k(const bf16* __restrict__ q_all,
                                              const bf16* __restrict__ k_all,
                                              const bf16* __restrict__ vt,
                                              bf16* __restrict__ attn_o) {
  const int qt = blockIdx.x;  // 24 q-tiles of 64
  const int n = blockIdx.y;   // head
  const int b = blockIdx.z;
  const int kv = n >> 1;
  const int tid = threadIdx.x, w = tid >> 6, l = tid & 63;
  const int lr = l & 15, lk = l >> 4;
  __shared__ __align__(16) bf16 Ksm[64 * 128];
  __shared__ __align__(16) bf16 Vsm[128 * 64];
  __shared__ __align__(16) bf16 Psm[4][16][72];

  bf16x8 qf[4];
  {
    int t = qt * 64 + w * 16 + lr;
    const bf16* qp = q_all + ((size_t)(b * TT + t) * NHQ + n) * HDM;
    #pragma unroll
    for (int kk = 0; kk < 4; kk++)
      qf[kk] = *reinterpret_cast<const bf16x8*>(qp + kk * 32 + lk * 8);
  }
  f32x4 acc_o[8];
  #pragma unroll
  for (int i = 0; i < 8; i++) acc_o[i] = (f32x4){0.f, 0.f, 0.f, 0.f};
  float den[4] = {0.f, 0.f, 0.f, 0.f};

  for (int st = 0; st < TT / 64; st++) {
    __syncthreads();
    #pragma unroll
    for (int i = 0; i < 4; i++) {
      int cb = (w * 4 + i) * 64;
      int c = cb + l;
      {
        int srow = c >> 4, c16 = c & 15;
        const bf16* g = k_all + ((size_t)(b * TT + st * 64 + srow) * NKVH + kv) * HDM +
                        ((c16 ^ (srow & 7)) << 3);
        async_load16(g, Ksm + cb * 8);
      }
      {
        int hrow = c >> 3, c8 = c & 7;
        const bf16* g = vt + ((size_t)(b * NKVH + kv) * HDM + hrow) * TT + st * 64 +
                        ((c8 ^ (hrow & 7)) << 3);
        async_load16(g, Vsm + cb * 8);
      }
    }
    __syncthreads();
    #pragma unroll
    for (int sf = 0; sf < 4; sf++) {
      f32x4 s4 = (f32x4){0.f, 0.f, 0.f, 0.f};
      int sl = sf * 16 + lr;
      #pragma unroll
      for (int kk = 0; kk < 4; kk++) {
        int e = kk * 32 + lk * 8;
        bf16x8 kf = *reinterpret_cast<const bf16x8*>(
            Ksm + sl * 128 + ((((e >> 3) ^ (sl & 7))) << 3));
        s4 = mfma16(qf[kk], kf, s4);
      }
      #pragma unroll
      for (int j = 0; j < 4; j++) {
        float xv = s4[j];
        float tcap = tanhf(xv * 0.02f) * 50.f;
        float p = __expf(tcap);
        Psm[w][lk * 4 + j][sf * 16 + lr] = f2bf(p);
        p += __shfl_xor(p, 1);
        p += __shfl_xor(p, 2);
        p += __shfl_xor(p, 4);
        p += __shfl_xor(p, 8);
        den[j] += p;
      }
    }
    #pragma unroll
    for (int kk2 = 0; kk2 < 2; kk2++) {
      bf16x8 pa = *reinterpret_cast<const bf16x8*>(&Psm[w][lr][kk2 * 32 + lk * 8]);
      #pragma unroll
      for (int hf = 0; hf < 8; hf++) {
        int h = hf * 16 + lr;
        int e2 = kk2 * 32 + lk * 8;
        bf16x8 vb = *reinterpret_cast<const bf16x8*>(
            Vsm + h * 64 + ((((e2 >> 3) ^ (h & 7))) << 3));
        acc_o[hf] = mfma16(pa, vb, acc_o[hf]);
      }
    }
  }
  #pragma unroll
  for (int hf = 0; hf < 8; hf++)
    #pragma unroll
    for (int j = 0; j < 4; j++) {
      int t = qt * 64 + w * 16 + lk * 4 + j;
      float val = acc_o[hf][j] / den[j];
      attn_o[((size_t)(b * TT + t)) * (NHQ * HDM) + n * HDM + hf * 16 + lr] = f2bf(val);
    }
}

// ---------------------------------------------------------------------------
extern "C" void kernel_launch(void* const* d_in, const int* in_sizes, int n_in,
                              void* d_out, int out_size, void* d_ws,
                              size_t ws_size, hipStream_t stream) {
  const float* x_img = (const float*)d_in[0];
  const float* x_txt = (const float*)d_in[1];
  const float* sc_attn_i = (const float*)d_in[3];
  const float* wq_i = (const float*)d_in[4];
  const float* wk_i = (const float*)d_in[5];
  const float* wv_i = (const float*)d_in[6];
  const float* wo_i = (const float*)d_in[7];
  const float* sc_ffw_i = (const float*)d_in[8];
  const float* wg_i = (const float*)d_in[9];
  const float* wu_i = (const float*)d_in[10];
  const float* wd_i = (const float*)d_in[11];
  const float* sc_attn_t = (const float*)d_in[12];
  const float* wq_t = (const float*)d_in[13];
  const float* wk_t = (const float*)d_in[14];
  const float* wv_t = (const float*)d_in[15];
  const float* wo_t = (const float*)d_in[16];
  const float* sc_ffw_t = (const float*)d_in[17];
  const float* wg_t = (const float*)d_in[18];
  const float* wu_t = (const float*)d_in[19];
  const float* wd_t = (const float*)d_in[20];
  float* outp = (float*)d_out;

  char* ws = (char*)d_ws;
  size_t off = 0;
  auto alloc = [&](size_t n) {
    char* p = ws + off;
    off += (n + 255) & ~(size_t)255;
    return p;
  };
  // persistent: bf16 transposed weights [N][K]
  bf16* WqT_i = (bf16*)alloc((size_t)2048 * 2048 * 2);
  bf16* WkT_i = (bf16*)alloc((size_t)1024 * 2048 * 2);
  bf16* WvT_i = (bf16*)alloc((size_t)1024 * 2048 * 2);
  bf16* WoT_i = (bf16*)alloc((size_t)2048 * 2048 * 2);
  bf16* WguT_i = (bf16*)alloc((size_t)16384 * 2048 * 2);  // Wg rows 0..8191, Wu rows 8192..
  bf16* WdT_i = (bf16*)alloc((size_t)2048 * 8192 * 2);
  bf16* WqT_t = (bf16*)alloc((size_t)2048 * 1024 * 2);
  bf16* WkT_t = (bf16*)alloc((size_t)1024 * 1024 * 2);
  bf16* WvT_t = (bf16*)alloc((size_t)1024 * 1024 * 2);
  bf16* WoT_t = (bf16*)alloc((size_t)1024 * 2048 * 2);
  bf16* WguT_t = (bf16*)alloc((size_t)8192 * 1024 * 2);
  bf16* WdT_t = (bf16*)alloc((size_t)1024 * 4096 * 2);
  // persistent activations
  bf16* xn_i = (bf16*)alloc((size_t)2048 * 2048 * 2);
  bf16* xn_t = (bf16*)alloc((size_t)1024 * 1024 * 2);
  // scratch region S (unions)
  float* h_i = (float*)alloc((size_t)2048 * 2048 * 4);
  float* h_t = (float*)alloc((size_t)1024 * 1024 * 4);
  char* S = (char*)alloc((size_t)84 * 1024 * 1024);  // phaseA / phaseB union
  (void)ws_size;
  // phase A layout within S
  bf16* q_all = (bf16*)S;                                    // 12 MB
  bf16* k_all = (bf16*)(S + 12582912);                       // 6 MB
  bf16* v_all = (bf16*)(S + 18874368);                       // 6 MB
  bf16* vtr   = (bf16*)(S + 25165824);                       // 6 MB
  bf16* attn_o= (bf16*)(S + 31457280);                       // 12 MB
  // phase B layout within S (after attn_o dead)
  bf16* gu_i  = (bf16*)S;                                    // 64 MB
  bf16* gu_t  = (bf16*)(S + (size_t)2048 * 16384 * 2);       // 16 MB

  // 1. weight transpose/convert (gate/up write into concatenated WguT)
  TJobs tj;
  auto setj = [&](int idx, const float* s, bf16* d, int K, int N) {
    tj.j[idx].src = s; tj.j[idx].dst = d; tj.j[idx].K = K; tj.j[idx].N = N;
  };
  setj(0, wq_i, WqT_i, 2048, 2048);
  setj(1, wk_i, WkT_i, 2048, 1024);
  setj(2, wv_i, WvT_i, 2048, 1024);
  setj(3, wo_i, WoT_i, 2048, 2048);
  setj(4, wg_i, WguT_i, 2048, 8192);
  setj(5, wu_i, WguT_i + (size_t)8192 * 2048, 2048, 8192);
  setj(6, wd_i, WdT_i, 8192, 2048);
  setj(7, wq_t, WqT_t, 1024, 2048);
  setj(8, wk_t, WkT_t, 1024, 1024);
  setj(9, wv_t, WvT_t, 1024, 1024);
  setj(10, wo_t, WoT_t, 2048, 1024);
  setj(11, wg_t, WguT_t, 1024, 4096);
  setj(12, wu_t, WguT_t + (size_t)4096 * 1024, 1024, 4096);
  setj(13, wd_t, WdT_t, 4096, 1024);
  tj.cum[0] = 0;
  for (int i = 0; i < 14; i++)
    tj.cum[i + 1] = tj.cum[i] + (tj.j[i].K >> 6) * (tj.j[i].N >> 6);
  wt_transpose<<<tj.cum[14], 256, 0, stream>>>(tj);

  // 2. pre-attn RMSNorm
  rmsnorm_k<2><<<2048, 256, 0, stream>>>(x_img, sc_attn_i, xn_i);
  rmsnorm_k<1><<<1024, 256, 0, stream>>>(x_txt, sc_attn_t, xn_t);

  auto mkjob = [](const bf16* A, const bf16* B, bf16* Cb, float* Cf,
                  const float* resid, int K, int N, int lda, int ab, int ash,
                  int ask, int cb2, int csh, int csk, int cstr) {
    GJob g;
    g.A = A; g.B = B; g.Cb = Cb; g.Cf = Cf; g.resid = resid;
    g.K = K; g.N = N; g.lda = lda;
    g.a_base = ab; g.a_lsh = ash; g.a_lskip = ask;
    g.c_base = cb2; g.c_lsh = csh; g.c_lskip = csk; g.c_stride = cstr;
    return g;
  };
  auto launch_gemm = [&](GJobs& P, int nj, int Mblk[]) {
    P.nj = nj;
    P.cum[0] = 0;
    for (int i = 0; i < nj; i++)
      P.cum[i + 1] = P.cum[i] + Mblk[i] * (P.j[i].N >> 7);
    gemm_uni<<<P.cum[nj], 256, 0, stream>>>(P);
  };

  // 3. QKV (img: rows remap m+(m>>10)*512; txt: 1024+m+(m>>9)*1024)
  {
    GJobs P;
    P.j[0] = mkjob(xn_i, WqT_i, q_all, nullptr, nullptr, 2048, 2048, 2048, 0, 30, 0, 0, 10, 512, 2048);
    P.j[1] = mkjob(xn_i, WkT_i, k_all, nullptr, nullptr, 2048, 1024, 2048, 0, 30, 0, 0, 10, 512, 1024);
    P.j[2] = mkjob(xn_i, WvT_i, v_all, nullptr, nullptr, 2048, 1024, 2048, 0, 30, 0, 0, 10, 512, 1024);
    P.j[3] = mkjob(xn_t, WqT_t, q_all, nullptr, nullptr, 1024, 2048, 1024, 0, 30, 0, 1024, 9, 1024, 2048);
    P.j[4] = mkjob(xn_t, WkT_t, k_all, nullptr, nullptr, 1024, 1024, 1024, 0, 30, 0, 1024, 9, 1024, 1024);
    P.j[5] = mkjob(xn_t, WvT_t, v_all, nullptr, nullptr, 1024, 1024, 1024, 0, 30, 0, 1024, 9, 1024, 1024);
    int mb[6] = {16, 16, 16, 8, 8, 8};
    launch_gemm(P, 6, mb);
  }

  // 4. RoPE
  rope_inplace<<<12288, 256, 0, stream>>>(q_all, 4, 0.08838834764831845f);
  rope_inplace<<<6144, 256, 0, stream>>>(k_all, 3, 1.0f);

  // 5. V transpose
  transpose_v<<<dim3(24, 2, 16), 256, 0, stream>>>(v_all, vtr);

  // 6. attention
  attn_k<<<dim3(24, 16, 2), 256, 0, stream>>>(q_all, k_all, vtr, attn_o);

  // 7. WO + residual -> h (f32); A reads attn_o with concat-row remap
  {
    GJobs P;
    P.j[0] = mkjob(attn_o, WoT_i, nullptr, h_i, x_img, 2048, 2048, 2048, 0, 10, 512, 0, 0, 0, 2048);
    P.j[1] = mkjob(attn_o, WoT_t, nullptr, h_t, x_txt, 2048, 1024, 2048, 1024, 9, 1024, 0, 0, 0, 1024);
    int mb[2] = {16, 8};
    launch_gemm(P, 2, mb);
  }

  // 8. pre-FFW RMSNorm (reuse xn)
  rmsnorm_k<2><<<2048, 256, 0, stream>>>(h_i, sc_ffw_i, xn_i);
  rmsnorm_k<1><<<1024, 256, 0, stream>>>(h_t, sc_ffw_t, xn_t);

  // 9. gate|up concatenated GEMM -> gu (bf16), then in-place GELU*mul
  {
    GJobs P;
    P.j[0] = mkjob(xn_i, WguT_i, gu_i, nullptr, nullptr, 2048, 16384, 2048, 0, 30, 0, 0, 30, 0, 16384);
    P.j[1] = mkjob(xn_t, WguT_t, gu_t, nullptr, nullptr, 1024, 8192, 1024, 0, 30, 0, 0, 30, 0, 8192);
    int mb[2] = {16, 8};
    launch_gemm(P, 2, mb);
  }
  {
    int total = 2048 * 8192 / 8 + 1024 * 4096 / 8;
    gelu_mul<<<(total + 255) / 256, 256, 0, stream>>>(gu_i, gu_t);
  }

  // 10. down GEMM + residual -> d_out (A = act in gate half of gu, lda = 2*half)
  {
    GJobs P;
    P.j[0] = mkjob(gu_i, WdT_i, nullptr, outp, x_img, 8192, 2048, 16384, 0, 30, 0, 0, 0, 0, 2048);
    P.j[1] = mkjob(gu_t, WdT_t, nullptr, outp + (size_t)2 * 1024 * 2048, x_txt, 4096, 1024, 8192, 0, 30, 0, 0, 0, 0, 1024);
    int mb[2] = {16, 8};
    launch_gemm(P, 2, mb);
  }
}

// Round 4
// 761.568 us; speedup vs baseline: 1.4328x; 1.1144x over previous
//
#include <hip/hip_runtime.h>
#include <hip/hip_bf16.h>

// MoE (img/txt mixture) transformer block for MI355X.
// Round 4: fixed 8-phase 256x256 GEMM (race-free stage schedule: B-halves
// staged at q2, A-halves at q3, vmcnt(8) counted wait) for qkv and gate|up;
// 128x128 2-phase gemm_uni for wo and down; flash attention with softcap.

typedef __hip_bfloat16 bf16;
typedef __attribute__((ext_vector_type(8))) __bf16 bf16x8;
typedef __attribute__((ext_vector_type(4))) float f32x4;

#define DEV __device__ __forceinline__

static constexpr int TT = 1536;
static constexpr int NHQ = 16, NKVH = 8, HDM = 128;

DEV void async_load16(const void* g, void* l) {
  typedef const __attribute__((address_space(1))) void* gas_t;
  typedef __attribute__((address_space(3))) void* las_t;
  __builtin_amdgcn_global_load_lds((gas_t)g, (las_t)l, 16, 0, 0);
}

DEV f32x4 mfma16(bf16x8 a, bf16x8 b, f32x4 c) {
  return __builtin_amdgcn_mfma_f32_16x16x32_bf16(a, b, c, 0, 0, 0);
}

DEV float bf2f(bf16 x) { return __bfloat162float(x); }
DEV bf16  f2bf(float x) { return __float2bfloat16(x); }

// ---------------------------------------------------------------------------
// Weight transpose+convert: f32 [K][N] -> bf16 [N][K]
// ---------------------------------------------------------------------------
struct TJob { const float* src; bf16* dst; int K; int N; };
struct TJobs { TJob j[14]; int cum[15]; };

__global__ __launch_bounds__(256) void wt_transpose(TJobs P) {
  __shared__ bf16 tile[64][65];
  int bid = blockIdx.x;
  int ji = 0;
  while (ji < 13 && bid >= P.cum[ji + 1]) ji++;
  const TJob jb = P.j[ji];
  int rel = bid - P.cum[ji];
  int ntc = jb.N >> 6;
  int tr = rel / ntc, tc = rel - tr * ntc;
  int r0 = tr << 6, c0 = tc << 6;
  int t = threadIdx.x;
  #pragma unroll
  for (int i = 0; i < 16; i++) {
    int idx = i * 256 + t;
    int r = idx >> 6, c = idx & 63;
    tile[c][r] = f2bf(jb.src[(size_t)(r0 + r) * jb.N + c0 + c]);
  }
  __syncthreads();
  #pragma unroll
  for (int i = 0; i < 16; i++) {
    int idx = i * 256 + t;
    int r = idx >> 6, c = idx & 63;
    jb.dst[(size_t)(c0 + r) * jb.K + r0 + c] = tile[r][c];
  }
}

// bf16 transpose for V: v_all [B*TT][NKVH*HDM] -> vt [B*NKVH][HDM][TT]
__global__ __launch_bounds__(256) void transpose_v(const bf16* __restrict__ v_all,
                                                   bf16* __restrict__ vt) {
  int st = blockIdx.x, ht = blockIdx.y, bk = blockIdx.z;
  int b = bk >> 3, kv = bk & 7;
  __shared__ bf16 tile[64][65];
  int t = threadIdx.x;
  int s0 = st * 64, h0 = ht * 64;
  #pragma unroll
  for (int i = 0; i < 16; i++) {
    int idx = i * 256 + t;
    int r = idx >> 6, c = idx & 63;
    tile[c][r] = v_all[((size_t)(b * TT + s0 + r) * NKVH + kv) * HDM + h0 + c];
  }
  __syncthreads();
  #pragma unroll
  for (int i = 0; i < 16; i++) {
    int idx = i * 256 + t;
    int r = idx >> 6, c = idx & 63;
    vt[((size_t)bk * HDM + h0 + r) * TT + s0 + c] = tile[r][c];
  }
}

// ---------------------------------------------------------------------------
// RMSNorm
// ---------------------------------------------------------------------------
template <int DV>
__global__ __launch_bounds__(256) void rmsnorm_k(const float* __restrict__ x,
                                                 const float* __restrict__ sc,
                                                 bf16* __restrict__ out) {
  const int D = DV * 1024;
  int row = blockIdx.x, t = threadIdx.x;
  const float4* xr = reinterpret_cast<const float4*>(x + (size_t)row * D);
  float4 v[DV];
  float ss = 0.f;
  #pragma unroll
  for (int i = 0; i < DV; i++) {
    v[i] = xr[t + i * 256];
    ss += v[i].x * v[i].x + v[i].y * v[i].y + v[i].z * v[i].z + v[i].w * v[i].w;
  }
  #pragma unroll
  for (int o = 1; o < 64; o <<= 1) ss += __shfl_xor(ss, o);
  __shared__ float red[4];
  if ((t & 63) == 0) red[t >> 6] = ss;
  __syncthreads();
  float r = rsqrtf((red[0] + red[1] + red[2] + red[3]) * (1.0f / D) + 1e-6f);
  bf16* orow = out + (size_t)row * D;
  #pragma unroll
  for (int i = 0; i < DV; i++) {
    int c = (t + i * 256) * 4;
    orow[c + 0] = f2bf(v[i].x * r * (1.f + sc[c + 0]));
    orow[c + 1] = f2bf(v[i].y * r * (1.f + sc[c + 1]));
    orow[c + 2] = f2bf(v[i].z * r * (1.f + sc[c + 2]));
    orow[c + 3] = f2bf(v[i].w * r * (1.f + sc[c + 3]));
  }
}

// ---------------------------------------------------------------------------
// RoPE in-place
// ---------------------------------------------------------------------------
__global__ __launch_bounds__(256) void rope_inplace(bf16* __restrict__ x, int lognh,
                                                    float scale) {
  int gid = blockIdx.x * 256 + threadIdx.x;
  int i = gid & 63;
  int rh = gid >> 6;
  int row = rh >> lognh;
  int pos = row >= TT ? row - TT : row;
  float fr = expf(-9.210340371976184f * ((float)(2 * i) * (1.0f / 128.0f)));
  float th = (float)pos * fr;
  float s, c;
  sincosf(th, &s, &c);
  bf16* p = x + (size_t)rh * HDM;
  float x1 = bf2f(p[i]), x2 = bf2f(p[i + 64]);
  p[i]      = f2bf((x1 * c - x2 * s) * scale);
  p[i + 64] = f2bf((x2 * c + x1 * s) * scale);
}

// ---------------------------------------------------------------------------
// 8-phase 256x256 GEMM (T2+T3+T4+T5). B stored [N][K]. Output bf16 with
// optional C row remap. 512 threads (8 waves, 2Mx4N), BK=64, 128 KiB LDS.
// Race-free stage schedule: within K-tile t, stage tile t+2 into the
// CURRENT buffer (t&1) only into regions already fully consumed:
//   q2: B0,B1 (B reads retire at end-of-q1 barrier)
//   q3: A0,A1 (A reads retire at end-of-q2 barrier)
// vmcnt(8) at q3 (8 loads/wave in flight = tile t+2) => tile t+1 resident.
// ---------------------------------------------------------------------------
struct G8Job {
  const bf16* A; const bf16* B; bf16* Cb;
  int K, N, lda;
  int c_base, c_lsh, c_lskip, c_stride;
};
struct G8Jobs { G8Job j[6]; int cum[7]; int nj; };

#define G8_BAR_MFMA(MH, NH)                                        \
  __builtin_amdgcn_s_barrier();                                    \
  asm volatile("s_waitcnt lgkmcnt(0)" ::: "memory");               \
  __builtin_amdgcn_sched_barrier(0);                               \
  __builtin_amdgcn_s_setprio(1);                                   \
  _Pragma("unroll")                                                \
  for (int i = 0; i < 4; i++)                                      \
    _Pragma("unroll")                                              \
    for (int nj2 = 0; nj2 < 2; nj2++)                              \
      _Pragma("unroll")                                            \
      for (int kk = 0; kk < 2; kk++)                               \
        acc[(MH)*4 + i][(NH)*2 + nj2] = mfma16(                    \
            afr[i][kk], bfr[(NH)*2 + nj2][kk],                     \
            acc[(MH)*4 + i][(NH)*2 + nj2]);                        \
  __builtin_amdgcn_s_setprio(0);                                   \
  __builtin_amdgcn_s_barrier();                                    \
  asm volatile("" ::: "memory");

__global__ __launch_bounds__(512, 2) void gemm8(G8Jobs P) {
  extern __shared__ __align__(16) bf16 lds8[];  // 2 buf x 4 half x 8192 el
  int bid = blockIdx.x;
  int ji = 0;
  while (ji < P.nj - 1 && bid >= P.cum[ji + 1]) ji++;
  const G8Job jb = P.j[ji];
  int rel = bid - P.cum[ji];
  int tn = jb.N >> 8;
  int bm = rel / tn, bn = rel - bm * tn;
  const int m0 = bm << 8, n0 = bn << 8;
  const int K = jb.K;
  const int nk = K >> 6;

  const int tid = threadIdx.x;
  const int w = tid >> 6, l = tid & 63;
  const int lr = l & 15, lk = l >> 4;
  const int wr = w >> 2, wc = w & 3;

  // staging: thread covers row r0 (and r1=64+r0) of a 128-row half-tile;
  // source slot XOR-swizzled, LDS dest linear (rule 21: swz source + swz read)
  const int r0 = tid >> 3, sl0 = (tid & 7) ^ (r0 & 7);
  const int dst0 = (w * 64) * 8;
  const int dst1 = (512 + w * 64) * 8;

  auto stage = [&](int ht, int hq) {
    int k0 = ht << 6;
    bf16* ldsb = lds8 + ((ht & 1) * 32768 + hq * 8192);
    if (hq < 2) {
      int ma = m0 + hq * 128;
      async_load16(jb.A + (size_t)(ma + r0) * jb.lda + k0 + sl0 * 8, ldsb + dst0);
      async_load16(jb.A + (size_t)(ma + 64 + r0) * jb.lda + k0 + sl0 * 8, ldsb + dst1);
    } else {
      int nb = n0 + (hq - 2) * 128;
      async_load16(jb.B + (size_t)(nb + r0) * K + k0 + sl0 * 8, ldsb + dst0);
      async_load16(jb.B + (size_t)(nb + 64 + r0) * K + k0 + sl0 * 8, ldsb + dst1);
    }
  };

  f32x4 acc[8][4];
  #pragma unroll
  for (int i = 0; i < 8; i++)
    #pragma unroll
    for (int j = 0; j < 4; j++) acc[i][j] = (f32x4){0.f, 0.f, 0.f, 0.f};

  // swizzled 16B-slot offsets for fragment reads (row&7 == lr&7 always)
  const int s0 = ((0 * 4 + lk) ^ (lr & 7)) * 8;
  const int s1 = ((1 * 4 + lk) ^ (lr & 7)) * 8;
  const int browb = (wc & 1) * 64;

  // prologue: tiles 0 and 1 fully staged (16 loads/wave)
  #pragma unroll
  for (int hq = 0; hq < 4; hq++) stage(0, hq);
  #pragma unroll
  for (int hq = 0; hq < 4; hq++) stage(1, hq);
  asm volatile("s_waitcnt vmcnt(8)" ::: "memory");  // tile 0 resident
  __builtin_amdgcn_s_barrier();
  asm volatile("" ::: "memory");

  bf16x8 afr[4][2], bfr[4][2];

  for (int t = 0; t < nk; t++) {
    const bf16* bufA = lds8 + (t & 1) * 32768 + wr * 8192;
    const bf16* bufB = lds8 + (t & 1) * 32768 + 16384 + (wc >> 1) * 8192;
    const bool st = (t + 2 < nk);

    // ---- phase q0: read A rows 0..63 + B rows browb+0..31; MFMA (0,0) ----
    #pragma unroll
    for (int i = 0; i < 4; i++) {
      int rb = (i * 16 + lr) * 64;
      afr[i][0] = *reinterpret_cast<const bf16x8*>(bufA + rb + s0);
      afr[i][1] = *reinterpret_cast<const bf16x8*>(bufA + rb + s1);
    }
    #pragma unroll
    for (int ni = 0; ni < 2; ni++) {
      int rb = (browb + ni * 16 + lr) * 64;
      bfr[ni][0] = *reinterpret_cast<const bf16x8*>(bufB + rb + s0);
      bfr[ni][1] = *reinterpret_cast<const bf16x8*>(bufB + rb + s1);
    }
    G8_BAR_MFMA(0, 0)

    // ---- phase q1: read B rows browb+32..63; MFMA (0,1) ----
    #pragma unroll
    for (int ni = 2; ni < 4; ni++) {
      int rb = (browb + ni * 16 + lr) * 64;
      bfr[ni][0] = *reinterpret_cast<const bf16x8*>(bufB + rb + s0);
      bfr[ni][1] = *reinterpret_cast<const bf16x8*>(bufB + rb + s1);
    }
    G8_BAR_MFMA(0, 1)

    // ---- phase q2: read A rows 64..127; stage B-halves of tile t+2 ----
    #pragma unroll
    for (int i = 0; i < 4; i++) {
      int rb = ((i + 4) * 16 + lr) * 64;
      afr[i][0] = *reinterpret_cast<const bf16x8*>(bufA + rb + s0);
      afr[i][1] = *reinterpret_cast<const bf16x8*>(bufA + rb + s1);
    }
    if (st) { stage(t + 2, 2); stage(t + 2, 3); }
    G8_BAR_MFMA(1, 0)

    // ---- phase q3: stage A-halves of tile t+2; counted vmcnt; MFMA (1,1) ----
    if (st) {
      stage(t + 2, 0); stage(t + 2, 1);
      asm volatile("s_waitcnt vmcnt(8)" ::: "memory");  // tile t+1 resident
    } else if (t == nk - 2) {
      asm volatile("s_waitcnt vmcnt(0)" ::: "memory");  // drain for last tile
    }
    G8_BAR_MFMA(1, 1)
  }

  // epilogue: write 128x64 per wave, bf16, with C row remap
  #pragma unroll
  for (int mi = 0; mi < 8; mi++)
    #pragma unroll
    for (int jj = 0; jj < 4; jj++) {
      int m = m0 + wr * 128 + mi * 16 + lk * 4 + jj;
      int crow = jb.c_base + m + ((m >> jb.c_lsh) * jb.c_lskip);
      bf16* drow = jb.Cb + (size_t)crow * jb.c_stride + n0 + wc * 64;
      #pragma unroll
      for (int ni = 0; ni < 4; ni++) drow[ni * 16 + lr] = f2bf(acc[mi][ni][jj]);
    }
}

// ---------------------------------------------------------------------------
// 128x128 2-phase GEMM (m97) for wo / down: f32 out + optional residual.
// ---------------------------------------------------------------------------
struct GJob {
  const bf16* A; const bf16* B;
  float* Cf; const float* resid;
  int K, N, lda;
  int a_base, a_lsh, a_lskip;
  int c_stride;
};
struct GJobs { GJob j[6]; int cum[7]; int nj; };

__global__ __launch_bounds__(256) void gemm_uni(GJobs P) {
  __shared__ __align__(16) bf16 As[128 * 64];
  __shared__ __align__(16) bf16 Bs[128 * 64];
  int bid = blockIdx.x;
  int ji = 0;
  while (ji < P.nj - 1 && bid >= P.cum[ji + 1]) ji++;
  const GJob jb = P.j[ji];
  int rel = bid - P.cum[ji];
  int tn = jb.N >> 7;
  int bm = rel / tn, bn = rel - bm * tn;
  int m0 = bm << 7, n0 = bn << 7;
  const bf16* Bp = jb.B + (size_t)n0 * jb.K;

  const int tid = threadIdx.x, w = tid >> 6, l = tid & 63;
  const int lr = l & 15, lk = l >> 4;
  const int wm = (w >> 1) * 64, wn = (w & 1) * 64;

  f32x4 acc[4][4];
  #pragma unroll
  for (int i = 0; i < 4; i++)
    #pragma unroll
    for (int jj = 0; jj < 4; jj++) acc[i][jj] = (f32x4){0.f, 0.f, 0.f, 0.f};

  const int K = jb.K;
  for (int k0 = 0; k0 < K; k0 += 64) {
    __syncthreads();
    #pragma unroll
    for (int i = 0; i < 4; i++) {
      int cb = (w * 4 + i) * 64;
      int c = cb + l;
      int row = c >> 3, c8 = c & 7;
      int m = m0 + row;
      int pr = jb.a_base + m + ((m >> jb.a_lsh) * jb.a_lskip);
      async_load16(jb.A + (size_t)pr * jb.lda + k0 + c8 * 8, As + cb * 8);
      async_load16(Bp + (size_t)row * K + k0 + c8 * 8, Bs + cb * 8);
    }
    __syncthreads();
    #pragma unroll
    for (int kk = 0; kk < 2; kk++) {
      bf16x8 af[4], bfr[4];
      #pragma unroll
      for (int mi = 0; mi < 4; mi++)
        af[mi] = *reinterpret_cast<const bf16x8*>(As + (wm + mi * 16 + lr) * 64 + kk * 32 + lk * 8);
      #pragma unroll
      for (int ni = 0; ni < 4; ni++)
        bfr[ni] = *reinterpret_cast<const bf16x8*>(Bs + (wn + ni * 16 + lr) * 64 + kk * 32 + lk * 8);
      #pragma unroll
      for (int mi = 0; mi < 4; mi++)
        #pragma unroll
        for (int ni = 0; ni < 4; ni++)
          acc[mi][ni] = mfma16(af[mi], bfr[ni], acc[mi][ni]);
    }
  }

  #pragma unroll
  for (int mi = 0; mi < 4; mi++)
    #pragma unroll
    for (int jj = 0; jj < 4; jj++) {
      int m = m0 + wm + mi * 16 + lk * 4 + jj;
      size_t ro = (size_t)m * jb.c_stride + n0 + wn;
      #pragma unroll
      for (int ni = 0; ni < 4; ni++) {
        int cc = ni * 16 + lr;
        float v = acc[mi][ni][jj];
        if (jb.resid) v += jb.resid[ro + cc];
        jb.Cf[ro + cc] = v;
      }
    }
}

// ---------------------------------------------------------------------------
// In-place GELU(gate)*up
// ---------------------------------------------------------------------------
__global__ __launch_bounds__(256) void gelu_mul(bf16* __restrict__ gu_i,
                                                bf16* __restrict__ gu_t) {
  const int IMG_CH = 2048 * 8192 / 8;
  const int TXT_CH = 1024 * 4096 / 8;
  int idx = blockIdx.x * 256 + threadIdx.x;
  int total = IMG_CH + TXT_CH;
  if (idx >= total) return;
  bf16* base;
  int half, ci;
  if (idx < IMG_CH) { base = gu_i; half = 8192; ci = idx; }
  else              { base = gu_t; half = 4096; ci = idx - IMG_CH; }
  int rowlen = half * 2;
  int perrow = half / 8;
  int m = ci / perrow, n8 = ci - m * perrow;
  bf16* gp = base + (size_t)m * rowlen + n8 * 8;
  bf16* up = gp + half;
  bf16x8 g8 = *reinterpret_cast<const bf16x8*>(gp);
  bf16x8 u8 = *reinterpret_cast<const bf16x8*>(up);
  bf16x8 o8;
  #pragma unroll
  for (int i = 0; i < 8; i++) {
    float g = (float)g8[i], u = (float)u8[i];
    float t = tanhf(0.7978845608028654f * (g + 0.044715f * g * g * g));
    o8[i] = (__bf16)(0.5f * g * (1.f + t) * u);
  }
  *reinterpret_cast<bf16x8*>(gp) = o8;
}

// ---------------------------------------------------------------------------
// Flash attention with softcap (no online max; logits bounded by +-50).
// ---------------------------------------------------------------------------
__global__ __launch_bounds__(256) void attn_k(const bf16* __restrict__ q_all,
                                              const bf16* __restrict__ k_all,
                                              const bf16* __restrict__ vt,
                                              bf16* __restrict__ attn_o) {
  const int qt = blockIdx.x;
  const int n = blockIdx.y;
  const int b = blockIdx.z;
  const int kv = n >> 1;
  const int tid = threadIdx.x, w = tid >> 6, l = tid & 63;
  const int lr = l & 15, lk = l >> 4;
  __shared__ __align__(16) bf16 Ksm[64 * 128];
  __shared__ __align__(16) bf16 Vsm[128 * 64];
  __shared__ __align__(16) bf16 Psm[4][16][72];

  bf16x8 qf[4];
  {
    int t = qt * 64 + w * 16 + lr;
    const bf16* qp = q_all + ((size_t)(b * TT + t) * NHQ + n) * HDM;
    #pragma unroll
    for (int kk = 0; kk < 4; kk++)
      qf[kk] = *reinterpret_cast<const bf16x8*>(qp + kk * 32 + lk * 8);
  }
  f32x4 acc_o[8];
  #pragma unroll
  for (int i = 0; i < 8; i++) acc_o[i] = (f32x4){0.f, 0.f, 0.f, 0.f};
  float den[4] = {0.f, 0.f, 0.f, 0.f};

  for (int st = 0; st < TT / 64; st++) {
    __syncthreads();
    #pragma unroll
    for (int i = 0; i < 4; i++) {
      int cb = (w * 4 + i) * 64;
      int c = cb + l;
      {
        int srow = c >> 4, c16 = c & 15;
        const bf16* g = k_all + ((size_t)(b * TT + st * 64 + srow) * NKVH + kv) * HDM +
                        ((c16 ^ (srow & 7)) << 3);
        async_load16(g, Ksm + cb * 8);
      }
      {
        int hrow = c >> 3, c8 = c & 7;
        const bf16* g = vt + ((size_t)(b * NKVH + kv) * HDM + hrow) * TT + st * 64 +
                        ((c8 ^ (hrow & 7)) << 3);
        async_load16(g, Vsm + cb * 8);
      }
    }
    __syncthreads();
    #pragma unroll
    for (int sf = 0; sf < 4; sf++) {
      f32x4 s4 = (f32x4){0.f, 0.f, 0.f, 0.f};
      int sl = sf * 16 + lr;
      #pragma unroll
      for (int kk = 0; kk < 4; kk++) {
        int e = kk * 32 + lk * 8;
        bf16x8 kf = *reinterpret_cast<const bf16x8*>(
            Ksm + sl * 128 + ((((e >> 3) ^ (sl & 7))) << 3));
        s4 = mfma16(qf[kk], kf, s4);
      }
      #pragma unroll
      for (int j = 0; j < 4; j++) {
        float xv = s4[j];
        float tcap = tanhf(xv * 0.02f) * 50.f;
        float p = __expf(tcap);
        Psm[w][lk * 4 + j][sf * 16 + lr] = f2bf(p);
        p += __shfl_xor(p, 1);
        p += __shfl_xor(p, 2);
        p += __shfl_xor(p, 4);
        p += __shfl_xor(p, 8);
        den[j] += p;
      }
    }
    #pragma unroll
    for (int kk2 = 0; kk2 < 2; kk2++) {
      bf16x8 pa = *reinterpret_cast<const bf16x8*>(&Psm[w][lr][kk2 * 32 + lk * 8]);
      #pragma unroll
      for (int hf = 0; hf < 8; hf++) {
        int h = hf * 16 + lr;
        int e2 = kk2 * 32 + lk * 8;
        bf16x8 vb = *reinterpret_cast<const bf16x8*>(
            Vsm + h * 64 + ((((e2 >> 3) ^ (h & 7))) << 3));
        acc_o[hf] = mfma16(pa, vb, acc_o[hf]);
      }
    }
  }
  #pragma unroll
  for (int hf = 0; hf < 8; hf++)
    #pragma unroll
    for (int j = 0; j < 4; j++) {
      int t = qt * 64 + w * 16 + lk * 4 + j;
      float val = acc_o[hf][j] / den[j];
      attn_o[((size_t)(b * TT + t)) * (NHQ * HDM) + n * HDM + hf * 16 + lr] = f2bf(val);
    }
}

// ---------------------------------------------------------------------------
extern "C" void kernel_launch(void* const* d_in, const int* in_sizes, int n_in,
                              void* d_out, int out_size, void* d_ws,
                              size_t ws_size, hipStream_t stream) {
  const float* x_img = (const float*)d_in[0];
  const float* x_txt = (const float*)d_in[1];
  const float* sc_attn_i = (const float*)d_in[3];
  const float* wq_i = (const float*)d_in[4];
  const float* wk_i = (const float*)d_in[5];
  const float* wv_i = (const float*)d_in[6];
  const float* wo_i = (const float*)d_in[7];
  const float* sc_ffw_i = (const float*)d_in[8];
  const float* wg_i = (const float*)d_in[9];
  const float* wu_i = (const float*)d_in[10];
  const float* wd_i = (const float*)d_in[11];
  const float* sc_attn_t = (const float*)d_in[12];
  const float* wq_t = (const float*)d_in[13];
  const float* wk_t = (const float*)d_in[14];
  const float* wv_t = (const float*)d_in[15];
  const float* wo_t = (const float*)d_in[16];
  const float* sc_ffw_t = (const float*)d_in[17];
  const float* wg_t = (const float*)d_in[18];
  const float* wu_t = (const float*)d_in[19];
  const float* wd_t = (const float*)d_in[20];
  float* outp = (float*)d_out;

  char* ws = (char*)d_ws;
  size_t off = 0;
  auto alloc = [&](size_t n) {
    char* p = ws + off;
    off += (n + 255) & ~(size_t)255;
    return p;
  };
  bf16* WqT_i = (bf16*)alloc((size_t)2048 * 2048 * 2);
  bf16* WkT_i = (bf16*)alloc((size_t)1024 * 2048 * 2);
  bf16* WvT_i = (bf16*)alloc((size_t)1024 * 2048 * 2);
  bf16* WoT_i = (bf16*)alloc((size_t)2048 * 2048 * 2);
  bf16* WguT_i = (bf16*)alloc((size_t)16384 * 2048 * 2);
  bf16* WdT_i = (bf16*)alloc((size_t)2048 * 8192 * 2);
  bf16* WqT_t = (bf16*)alloc((size_t)2048 * 1024 * 2);
  bf16* WkT_t = (bf16*)alloc((size_t)1024 * 1024 * 2);
  bf16* WvT_t = (bf16*)alloc((size_t)1024 * 1024 * 2);
  bf16* WoT_t = (bf16*)alloc((size_t)1024 * 2048 * 2);
  bf16* WguT_t = (bf16*)alloc((size_t)8192 * 1024 * 2);
  bf16* WdT_t = (bf16*)alloc((size_t)1024 * 4096 * 2);
  bf16* xn_i = (bf16*)alloc((size_t)2048 * 2048 * 2);
  bf16* xn_t = (bf16*)alloc((size_t)1024 * 1024 * 2);
  float* h_i = (float*)alloc((size_t)2048 * 2048 * 4);
  float* h_t = (float*)alloc((size_t)1024 * 1024 * 4);
  char* S = (char*)alloc((size_t)84 * 1024 * 1024);
  (void)ws_size;
  bf16* q_all = (bf16*)S;
  bf16* k_all = (bf16*)(S + 12582912);
  bf16* v_all = (bf16*)(S + 18874368);
  bf16* vtr   = (bf16*)(S + 25165824);
  bf16* attn_o= (bf16*)(S + 31457280);
  bf16* gu_i  = (bf16*)S;
  bf16* gu_t  = (bf16*)(S + (size_t)2048 * 16384 * 2);

  (void)hipFuncSetAttribute(reinterpret_cast<const void*>(gemm8),
                            hipFuncAttributeMaxDynamicSharedMemorySize, 131072);

  // 1. weight transpose/convert
  TJobs tj;
  auto setj = [&](int idx, const float* s, bf16* d, int K, int N) {
    tj.j[idx].src = s; tj.j[idx].dst = d; tj.j[idx].K = K; tj.j[idx].N = N;
  };
  setj(0, wq_i, WqT_i, 2048, 2048);
  setj(1, wk_i, WkT_i, 2048, 1024);
  setj(2, wv_i, WvT_i, 2048, 1024);
  setj(3, wo_i, WoT_i, 2048, 2048);
  setj(4, wg_i, WguT_i, 2048, 8192);
  setj(5, wu_i, WguT_i + (size_t)8192 * 2048, 2048, 8192);
  setj(6, wd_i, WdT_i, 8192, 2048);
  setj(7, wq_t, WqT_t, 1024, 2048);
  setj(8, wk_t, WkT_t, 1024, 1024);
  setj(9, wv_t, WvT_t, 1024, 1024);
  setj(10, wo_t, WoT_t, 2048, 1024);
  setj(11, wg_t, WguT_t, 1024, 4096);
  setj(12, wu_t, WguT_t + (size_t)4096 * 1024, 1024, 4096);
  setj(13, wd_t, WdT_t, 4096, 1024);
  tj.cum[0] = 0;
  for (int i = 0; i < 14; i++)
    tj.cum[i + 1] = tj.cum[i] + (tj.j[i].K >> 6) * (tj.j[i].N >> 6);
  wt_transpose<<<tj.cum[14], 256, 0, stream>>>(tj);

  // 2. pre-attn RMSNorm
  rmsnorm_k<2><<<2048, 256, 0, stream>>>(x_img, sc_attn_i, xn_i);
  rmsnorm_k<1><<<1024, 256, 0, stream>>>(x_txt, sc_attn_t, xn_t);

  auto mk8 = [](const bf16* A, const bf16* B, bf16* Cb, int K, int N, int lda,
                int cb2, int csh, int csk, int cstr) {
    G8Job g;
    g.A = A; g.B = B; g.Cb = Cb; g.K = K; g.N = N; g.lda = lda;
    g.c_base = cb2; g.c_lsh = csh; g.c_lskip = csk; g.c_stride = cstr;
    return g;
  };

  // 3. QKV via gemm8 (256^2 tiles)
  {
    G8Jobs P;
    P.j[0] = mk8(xn_i, WqT_i, q_all, 2048, 2048, 2048, 0, 10, 512, 2048);
    P.j[1] = mk8(xn_i, WkT_i, k_all, 2048, 1024, 2048, 0, 10, 512, 1024);
    P.j[2] = mk8(xn_i, WvT_i, v_all, 2048, 1024, 2048, 0, 10, 512, 1024);
    P.j[3] = mk8(xn_t, WqT_t, q_all, 1024, 2048, 1024, 1024, 9, 1024, 2048);
    P.j[4] = mk8(xn_t, WkT_t, k_all, 1024, 1024, 1024, 1024, 9, 1024, 1024);
    P.j[5] = mk8(xn_t, WvT_t, v_all, 1024, 1024, 1024, 1024, 9, 1024, 1024);
    int Mt[6] = {8, 8, 8, 4, 4, 4};
    P.nj = 6;
    P.cum[0] = 0;
    for (int i = 0; i < 6; i++) P.cum[i + 1] = P.cum[i] + Mt[i] * (P.j[i].N >> 8);
    gemm8<<<P.cum[6], 512, 131072, stream>>>(P);
  }

  // 4. RoPE
  rope_inplace<<<12288, 256, 0, stream>>>(q_all, 4, 0.08838834764831845f);
  rope_inplace<<<6144, 256, 0, stream>>>(k_all, 3, 1.0f);

  // 5. V transpose
  transpose_v<<<dim3(24, 2, 16), 256, 0, stream>>>(v_all, vtr);

  // 6. attention
  attn_k<<<dim3(24, 16, 2), 256, 0, stream>>>(q_all, k_all, vtr, attn_o);

  // 7. WO + residual -> h (f32)
  auto mkjob = [](const bf16* A, const bf16* B, float* Cf, const float* resid,
                  int K, int N, int lda, int ab, int ash, int ask, int cstr) {
    GJob g;
    g.A = A; g.B = B; g.Cf = Cf; g.resid = resid;
    g.K = K; g.N = N; g.lda = lda;
    g.a_base = ab; g.a_lsh = ash; g.a_lskip = ask; g.c_stride = cstr;
    return g;
  };
  {
    GJobs P;
    P.j[0] = mkjob(attn_o, WoT_i, h_i, x_img, 2048, 2048, 2048, 0, 10, 512, 2048);
    P.j[1] = mkjob(attn_o, WoT_t, h_t, x_txt, 2048, 1024, 2048, 1024, 9, 1024, 1024);
    int Mb[2] = {16, 8};
    P.nj = 2;
    P.cum[0] = 0;
    for (int i = 0; i < 2; i++) P.cum[i + 1] = P.cum[i] + Mb[i] * (P.j[i].N >> 7);
    gemm_uni<<<P.cum[2], 256, 0, stream>>>(P);
  }

  // 8. pre-FFW RMSNorm
  rmsnorm_k<2><<<2048, 256, 0, stream>>>(h_i, sc_ffw_i, xn_i);
  rmsnorm_k<1><<<1024, 256, 0, stream>>>(h_t, sc_ffw_t, xn_t);

  // 9. gate|up via gemm8 -> gu (bf16), then in-place GELU*mul
  {
    G8Jobs P;
    P.j[0] = mk8(xn_i, WguT_i, gu_i, 2048, 16384, 2048, 0, 30, 0, 16384);
    P.j[1] = mk8(xn_t, WguT_t, gu_t, 1024, 8192, 1024, 0, 30, 0, 8192);
    int Mt[2] = {8, 4};
    P.nj = 2;
    P.cum[0] = 0;
    for (int i = 0; i < 2; i++) P.cum[i + 1] = P.cum[i] + Mt[i] * (P.j[i].N >> 8);
    gemm8<<<P.cum[2], 512, 131072, stream>>>(P);
  }
  {
    int total = 2048 * 8192 / 8 + 1024 * 4096 / 8;
    gelu_mul<<<(total + 255) / 256, 256, 0, stream>>>(gu_i, gu_t);
  }

  // 10. down GEMM + residual -> d_out
  {
    GJobs P;
    P.j[0] = mkjob(gu_i, WdT_i, outp, x_img, 8192, 2048, 16384, 0, 30, 0, 2048);
    P.j[1] = mkjob(gu_t, WdT_t, outp + (size_t)2 * 1024 * 2048, x_txt, 4096, 1024,
                   8192, 0, 30, 0, 1024);
    int Mb[2] = {16, 8};
    P.nj = 2;
    P.cum[0] = 0;
    for (int i = 0; i < 2; i++) P.cum[i + 1] = P.cum[i] + Mb[i] * (P.j[i].N >> 7);
    gemm_uni<<<P.cum[2], 256, 0, stream>>>(P);
  }
}

// Round 5
// 665.575 us; speedup vs baseline: 1.6395x; 1.1442x over previous
//
#include <hip/hip_runtime.h>
#include <hip/hip_bf16.h>

// MoE (img/txt mixture) transformer block for MI355X.
// Round 5: ALL GEMMs on the 8-phase 256x256 gemm8 template; wo and down use
// deterministic split-K=2 (partials into dead ws regions + fused reduce).
// gemm8 gains ldb, A row-remap, f32 epilogue. gemm_uni retired.

typedef __hip_bfloat16 bf16;
typedef __attribute__((ext_vector_type(8))) __bf16 bf16x8;
typedef __attribute__((ext_vector_type(4))) float f32x4;

#define DEV __device__ __forceinline__

static constexpr int TT = 1536;
static constexpr int NHQ = 16, NKVH = 8, HDM = 128;

DEV void async_load16(const void* g, void* l) {
  typedef const __attribute__((address_space(1))) void* gas_t;
  typedef __attribute__((address_space(3))) void* las_t;
  __builtin_amdgcn_global_load_lds((gas_t)g, (las_t)l, 16, 0, 0);
}

DEV f32x4 mfma16(bf16x8 a, bf16x8 b, f32x4 c) {
  return __builtin_amdgcn_mfma_f32_16x16x32_bf16(a, b, c, 0, 0, 0);
}

DEV float bf2f(bf16 x) { return __bfloat162float(x); }
DEV bf16  f2bf(float x) { return __float2bfloat16(x); }

// ---------------------------------------------------------------------------
// Weight transpose+convert: f32 [K][N] -> bf16 [N][K]
// ---------------------------------------------------------------------------
struct TJob { const float* src; bf16* dst; int K; int N; };
struct TJobs { TJob j[14]; int cum[15]; };

__global__ __launch_bounds__(256) void wt_transpose(TJobs P) {
  __shared__ bf16 tile[64][65];
  int bid = blockIdx.x;
  int ji = 0;
  while (ji < 13 && bid >= P.cum[ji + 1]) ji++;
  const TJob jb = P.j[ji];
  int rel = bid - P.cum[ji];
  int ntc = jb.N >> 6;
  int tr = rel / ntc, tc = rel - tr * ntc;
  int r0 = tr << 6, c0 = tc << 6;
  int t = threadIdx.x;
  #pragma unroll
  for (int i = 0; i < 16; i++) {
    int idx = i * 256 + t;
    int r = idx >> 6, c = idx & 63;
    tile[c][r] = f2bf(jb.src[(size_t)(r0 + r) * jb.N + c0 + c]);
  }
  __syncthreads();
  #pragma unroll
  for (int i = 0; i < 16; i++) {
    int idx = i * 256 + t;
    int r = idx >> 6, c = idx & 63;
    jb.dst[(size_t)(c0 + r) * jb.K + r0 + c] = tile[r][c];
  }
}

// bf16 transpose for V: v_all [B*TT][NKVH*HDM] -> vt [B*NKVH][HDM][TT]
__global__ __launch_bounds__(256) void transpose_v(const bf16* __restrict__ v_all,
                                                   bf16* __restrict__ vt) {
  int st = blockIdx.x, ht = blockIdx.y, bk = blockIdx.z;
  int b = bk >> 3, kv = bk & 7;
  __shared__ bf16 tile[64][65];
  int t = threadIdx.x;
  int s0 = st * 64, h0 = ht * 64;
  #pragma unroll
  for (int i = 0; i < 16; i++) {
    int idx = i * 256 + t;
    int r = idx >> 6, c = idx & 63;
    tile[c][r] = v_all[((size_t)(b * TT + s0 + r) * NKVH + kv) * HDM + h0 + c];
  }
  __syncthreads();
  #pragma unroll
  for (int i = 0; i < 16; i++) {
    int idx = i * 256 + t;
    int r = idx >> 6, c = idx & 63;
    vt[((size_t)bk * HDM + h0 + r) * TT + s0 + c] = tile[r][c];
  }
}

// ---------------------------------------------------------------------------
// RMSNorm
// ---------------------------------------------------------------------------
template <int DV>
__global__ __launch_bounds__(256) void rmsnorm_k(const float* __restrict__ x,
                                                 const float* __restrict__ sc,
                                                 bf16* __restrict__ out) {
  const int D = DV * 1024;
  int row = blockIdx.x, t = threadIdx.x;
  const float4* xr = reinterpret_cast<const float4*>(x + (size_t)row * D);
  float4 v[DV];
  float ss = 0.f;
  #pragma unroll
  for (int i = 0; i < DV; i++) {
    v[i] = xr[t + i * 256];
    ss += v[i].x * v[i].x + v[i].y * v[i].y + v[i].z * v[i].z + v[i].w * v[i].w;
  }
  #pragma unroll
  for (int o = 1; o < 64; o <<= 1) ss += __shfl_xor(ss, o);
  __shared__ float red[4];
  if ((t & 63) == 0) red[t >> 6] = ss;
  __syncthreads();
  float r = rsqrtf((red[0] + red[1] + red[2] + red[3]) * (1.0f / D) + 1e-6f);
  bf16* orow = out + (size_t)row * D;
  #pragma unroll
  for (int i = 0; i < DV; i++) {
    int c = (t + i * 256) * 4;
    orow[c + 0] = f2bf(v[i].x * r * (1.f + sc[c + 0]));
    orow[c + 1] = f2bf(v[i].y * r * (1.f + sc[c + 1]));
    orow[c + 2] = f2bf(v[i].z * r * (1.f + sc[c + 2]));
    orow[c + 3] = f2bf(v[i].w * r * (1.f + sc[c + 3]));
  }
}

// ---------------------------------------------------------------------------
// RoPE in-place
// ---------------------------------------------------------------------------
__global__ __launch_bounds__(256) void rope_inplace(bf16* __restrict__ x, int lognh,
                                                    float scale) {
  int gid = blockIdx.x * 256 + threadIdx.x;
  int i = gid & 63;
  int rh = gid >> 6;
  int row = rh >> lognh;
  int pos = row >= TT ? row - TT : row;
  float fr = expf(-9.210340371976184f * ((float)(2 * i) * (1.0f / 128.0f)));
  float th = (float)pos * fr;
  float s, c;
  sincosf(th, &s, &c);
  bf16* p = x + (size_t)rh * HDM;
  float x1 = bf2f(p[i]), x2 = bf2f(p[i + 64]);
  p[i]      = f2bf((x1 * c - x2 * s) * scale);
  p[i + 64] = f2bf((x2 * c + x1 * s) * scale);
}

// ---------------------------------------------------------------------------
// 8-phase 256x256 GEMM (T2+T3+T4+T5). B stored [N][ldb] slice of length K.
// A row remap: phys_row = a_base + m + ((m>>a_lsh)*a_lskip). Output either
// bf16 with C row remap (Cb) or plain f32 (Cf). 512 threads, 128 KiB LDS.
// Race-free stage schedule (proven r4): q2 stages B-halves of tile t+2,
// q3 stages A-halves; vmcnt(8) at q3 => tile t+1 resident.
// ---------------------------------------------------------------------------
struct G8Job {
  const bf16* A; const bf16* B; bf16* Cb; float* Cf;
  int K, N, lda, ldb;
  int a_base, a_lsh, a_lskip;
  int c_base, c_lsh, c_lskip, c_stride;
};
struct G8Jobs { G8Job j[6]; int cum[7]; int nj; };

#define G8_BAR_MFMA(MH, NH)                                        \
  __builtin_amdgcn_s_barrier();                                    \
  asm volatile("s_waitcnt lgkmcnt(0)" ::: "memory");               \
  __builtin_amdgcn_sched_barrier(0);                               \
  __builtin_amdgcn_s_setprio(1);                                   \
  _Pragma("unroll")                                                \
  for (int i = 0; i < 4; i++)                                      \
    _Pragma("unroll")                                              \
    for (int nj2 = 0; nj2 < 2; nj2++)                              \
      _Pragma("unroll")                                            \
      for (int kk = 0; kk < 2; kk++)                               \
        acc[(MH)*4 + i][(NH)*2 + nj2] = mfma16(                    \
            afr[i][kk], bfr[(NH)*2 + nj2][kk],                     \
            acc[(MH)*4 + i][(NH)*2 + nj2]);                        \
  __builtin_amdgcn_s_setprio(0);                                   \
  __builtin_amdgcn_s_barrier();                                    \
  asm volatile("" ::: "memory");

__global__ __launch_bounds__(512, 2) void gemm8(G8Jobs P) {
  extern __shared__ __align__(16) bf16 lds8[];  // 2 buf x 4 half x 8192 el
  int bid = blockIdx.x;
  int ji = 0;
  while (ji < P.nj - 1 && bid >= P.cum[ji + 1]) ji++;
  const G8Job jb = P.j[ji];
  int rel = bid - P.cum[ji];
  int tn = jb.N >> 8;
  int bm = rel / tn, bn = rel - bm * tn;
  const int m0 = bm << 8, n0 = bn << 8;
  const int K = jb.K;
  const int nk = K >> 6;

  const int tid = threadIdx.x;
  const int w = tid >> 6, l = tid & 63;
  const int lr = l & 15, lk = l >> 4;
  const int wr = w >> 2, wc = w & 3;

  const int r0 = tid >> 3, sl0 = (tid & 7) ^ (r0 & 7);
  const int dst0 = (w * 64) * 8;
  const int dst1 = (512 + w * 64) * 8;

  auto stage = [&](int ht, int hq) {
    int k0 = ht << 6;
    bf16* ldsb = lds8 + ((ht & 1) * 32768 + hq * 8192);
    if (hq < 2) {
      int ma = m0 + hq * 128;
      int mr0 = ma + r0, mr1 = ma + 64 + r0;
      int pr0 = jb.a_base + mr0 + ((mr0 >> jb.a_lsh) * jb.a_lskip);
      int pr1 = jb.a_base + mr1 + ((mr1 >> jb.a_lsh) * jb.a_lskip);
      async_load16(jb.A + (size_t)pr0 * jb.lda + k0 + sl0 * 8, ldsb + dst0);
      async_load16(jb.A + (size_t)pr1 * jb.lda + k0 + sl0 * 8, ldsb + dst1);
    } else {
      int nb = n0 + (hq - 2) * 128;
      async_load16(jb.B + (size_t)(nb + r0) * jb.ldb + k0 + sl0 * 8, ldsb + dst0);
      async_load16(jb.B + (size_t)(nb + 64 + r0) * jb.ldb + k0 + sl0 * 8, ldsb + dst1);
    }
  };

  f32x4 acc[8][4];
  #pragma unroll
  for (int i = 0; i < 8; i++)
    #pragma unroll
    for (int j = 0; j < 4; j++) acc[i][j] = (f32x4){0.f, 0.f, 0.f, 0.f};

  const int s0 = ((0 * 4 + lk) ^ (lr & 7)) * 8;
  const int s1 = ((1 * 4 + lk) ^ (lr & 7)) * 8;
  const int browb = (wc & 1) * 64;

  #pragma unroll
  for (int hq = 0; hq < 4; hq++) stage(0, hq);
  #pragma unroll
  for (int hq = 0; hq < 4; hq++) stage(1, hq);
  asm volatile("s_waitcnt vmcnt(8)" ::: "memory");
  __builtin_amdgcn_s_barrier();
  asm volatile("" ::: "memory");

  bf16x8 afr[4][2], bfr[4][2];

  for (int t = 0; t < nk; t++) {
    const bf16* bufA = lds8 + (t & 1) * 32768 + wr * 8192;
    const bf16* bufB = lds8 + (t & 1) * 32768 + 16384 + (wc >> 1) * 8192;
    const bool st = (t + 2 < nk);

    #pragma unroll
    for (int i = 0; i < 4; i++) {
      int rb = (i * 16 + lr) * 64;
      afr[i][0] = *reinterpret_cast<const bf16x8*>(bufA + rb + s0);
      afr[i][1] = *reinterpret_cast<const bf16x8*>(bufA + rb + s1);
    }
    #pragma unroll
    for (int ni = 0; ni < 2; ni++) {
      int rb = (browb + ni * 16 + lr) * 64;
      bfr[ni][0] = *reinterpret_cast<const bf16x8*>(bufB + rb + s0);
      bfr[ni][1] = *reinterpret_cast<const bf16x8*>(bufB + rb + s1);
    }
    G8_BAR_MFMA(0, 0)

    #pragma unroll
    for (int ni = 2; ni < 4; ni++) {
      int rb = (browb + ni * 16 + lr) * 64;
      bfr[ni][0] = *reinterpret_cast<const bf16x8*>(bufB + rb + s0);
      bfr[ni][1] = *reinterpret_cast<const bf16x8*>(bufB + rb + s1);
    }
    G8_BAR_MFMA(0, 1)

    #pragma unroll
    for (int i = 0; i < 4; i++) {
      int rb = ((i + 4) * 16 + lr) * 64;
      afr[i][0] = *reinterpret_cast<const bf16x8*>(bufA + rb + s0);
      afr[i][1] = *reinterpret_cast<const bf16x8*>(bufA + rb + s1);
    }
    if (st) { stage(t + 2, 2); stage(t + 2, 3); }
    G8_BAR_MFMA(1, 0)

    if (st) {
      stage(t + 2, 0); stage(t + 2, 1);
      asm volatile("s_waitcnt vmcnt(8)" ::: "memory");
    } else if (t == nk - 2) {
      asm volatile("s_waitcnt vmcnt(0)" ::: "memory");
    }
    G8_BAR_MFMA(1, 1)
  }

  if (jb.Cf) {
    #pragma unroll
    for (int mi = 0; mi < 8; mi++)
      #pragma unroll
      for (int jj = 0; jj < 4; jj++) {
        int m = m0 + wr * 128 + mi * 16 + lk * 4 + jj;
        float* drow = jb.Cf + (size_t)m * jb.c_stride + n0 + wc * 64;
        #pragma unroll
        for (int ni = 0; ni < 4; ni++) drow[ni * 16 + lr] = acc[mi][ni][jj];
      }
  } else {
    #pragma unroll
    for (int mi = 0; mi < 8; mi++)
      #pragma unroll
      for (int jj = 0; jj < 4; jj++) {
        int m = m0 + wr * 128 + mi * 16 + lk * 4 + jj;
        int crow = jb.c_base + m + ((m >> jb.c_lsh) * jb.c_lskip);
        bf16* drow = jb.Cb + (size_t)crow * jb.c_stride + n0 + wc * 64;
        #pragma unroll
        for (int ni = 0; ni < 4; ni++) drow[ni * 16 + lr] = f2bf(acc[mi][ni][jj]);
      }
  }
}

// ---------------------------------------------------------------------------
// Split-K reduce: dst[i] += p1[i] + resid[i], two jobs, float4 grid-stride.
// ---------------------------------------------------------------------------
__global__ __launch_bounds__(256) void reduce_add(
    float* __restrict__ d0, const float* __restrict__ p0, const float* __restrict__ r0,
    int n40,
    float* __restrict__ d1, const float* __restrict__ p1, const float* __restrict__ r1,
    int n41) {
  int tot = n40 + n41;
  for (int idx = blockIdx.x * 256 + threadIdx.x; idx < tot; idx += gridDim.x * 256) {
    if (idx < n40) {
      float4 d = ((const float4*)d0)[idx];
      float4 p = ((const float4*)p0)[idx];
      float4 r = ((const float4*)r0)[idx];
      ((float4*)d0)[idx] = make_float4(d.x + p.x + r.x, d.y + p.y + r.y,
                                       d.z + p.z + r.z, d.w + p.w + r.w);
    } else {
      int i = idx - n40;
      float4 d = ((const float4*)d1)[i];
      float4 p = ((const float4*)p1)[i];
      float4 r = ((const float4*)r1)[i];
      ((float4*)d1)[i] = make_float4(d.x + p.x + r.x, d.y + p.y + r.y,
                                     d.z + p.z + r.z, d.w + p.w + r.w);
    }
  }
}

// ---------------------------------------------------------------------------
// In-place GELU(gate)*up
// ---------------------------------------------------------------------------
__global__ __launch_bounds__(256) void gelu_mul(bf16* __restrict__ gu_i,
                                                bf16* __restrict__ gu_t) {
  const int IMG_CH = 2048 * 8192 / 8;
  const int TXT_CH = 1024 * 4096 / 8;
  int idx = blockIdx.x * 256 + threadIdx.x;
  int total = IMG_CH + TXT_CH;
  if (idx >= total) return;
  bf16* base;
  int half, ci;
  if (idx < IMG_CH) { base = gu_i; half = 8192; ci = idx; }
  else              { base = gu_t; half = 4096; ci = idx - IMG_CH; }
  int rowlen = half * 2;
  int perrow = half / 8;
  int m = ci / perrow, n8 = ci - m * perrow;
  bf16* gp = base + (size_t)m * rowlen + n8 * 8;
  bf16* up = gp + half;
  bf16x8 g8 = *reinterpret_cast<const bf16x8*>(gp);
  bf16x8 u8 = *reinterpret_cast<const bf16x8*>(up);
  bf16x8 o8;
  #pragma unroll
  for (int i = 0; i < 8; i++) {
    float g = (float)g8[i], u = (float)u8[i];
    float t = tanhf(0.7978845608028654f * (g + 0.044715f * g * g * g));
    o8[i] = (__bf16)(0.5f * g * (1.f + t) * u);
  }
  *reinterpret_cast<bf16x8*>(gp) = o8;
}

// ---------------------------------------------------------------------------
// Flash attention with softcap (no online max; logits bounded by +-50).
// ---------------------------------------------------------------------------
__global__ __launch_bounds__(256) void attn_k(const bf16* __restrict__ q_all,
                                              const bf16* __restrict__ k_all,
                                              const bf16* __restrict__ vt,
                                              bf16* __restrict__ attn_o) {
  const int qt = blockIdx.x;
  const int n = blockIdx.y;
  const int b = blockIdx.z;
  const int kv = n >> 1;
  const int tid = threadIdx.x, w = tid >> 6, l = tid & 63;
  const int lr = l & 15, lk = l >> 4;
  __shared__ __align__(16) bf16 Ksm[64 * 128];
  __shared__ __align__(16) bf16 Vsm[128 * 64];
  __shared__ __align__(16) bf16 Psm[4][16][72];

  bf16x8 qf[4];
  {
    int t = qt * 64 + w * 16 + lr;
    const bf16* qp = q_all + ((size_t)(b * TT + t) * NHQ + n) * HDM;
    #pragma unroll
    for (int kk = 0; kk < 4; kk++)
      qf[kk] = *reinterpret_cast<const bf16x8*>(qp + kk * 32 + lk * 8);
  }
  f32x4 acc_o[8];
  #pragma unroll
  for (int i = 0; i < 8; i++) acc_o[i] = (f32x4){0.f, 0.f, 0.f, 0.f};
  float den[4] = {0.f, 0.f, 0.f, 0.f};

  for (int st = 0; st < TT / 64; st++) {
    __syncthreads();
    #pragma unroll
    for (int i = 0; i < 4; i++) {
      int cb = (w * 4 + i) * 64;
      int c = cb + l;
      {
        int srow = c >> 4, c16 = c & 15;
        const bf16* g = k_all + ((size_t)(b * TT + st * 64 + srow) * NKVH + kv) * HDM +
                        ((c16 ^ (srow & 7)) << 3);
        async_load16(g, Ksm + cb * 8);
      }
      {
        int hrow = c >> 3, c8 = c & 7;
        const bf16* g = vt + ((size_t)(b * NKVH + kv) * HDM + hrow) * TT + st * 64 +
                        ((c8 ^ (hrow & 7)) << 3);
        async_load16(g, Vsm + cb * 8);
      }
    }
    __syncthreads();
    #pragma unroll
    for (int sf = 0; sf < 4; sf++) {
      f32x4 s4 = (f32x4){0.f, 0.f, 0.f, 0.f};
      int sl = sf * 16 + lr;
      #pragma unroll
      for (int kk = 0; kk < 4; kk++) {
        int e = kk * 32 + lk * 8;
        bf16x8 kf = *reinterpret_cast<const bf16x8*>(
            Ksm + sl * 128 + ((((e >> 3) ^ (sl & 7))) << 3));
        s4 = mfma16(qf[kk], kf, s4);
      }
      #pragma unroll
      for (int j = 0; j < 4; j++) {
        float xv = s4[j];
        float tcap = tanhf(xv * 0.02f) * 50.f;
        float p = __expf(tcap);
        Psm[w][lk * 4 + j][sf * 16 + lr] = f2bf(p);
        p += __shfl_xor(p, 1);
        p += __shfl_xor(p, 2);
        p += __shfl_xor(p, 4);
        p += __shfl_xor(p, 8);
        den[j] += p;
      }
    }
    #pragma unroll
    for (int kk2 = 0; kk2 < 2; kk2++) {
      bf16x8 pa = *reinterpret_cast<const bf16x8*>(&Psm[w][lr][kk2 * 32 + lk * 8]);
      #pragma unroll
      for (int hf = 0; hf < 8; hf++) {
        int h = hf * 16 + lr;
        int e2 = kk2 * 32 + lk * 8;
        bf16x8 vb = *reinterpret_cast<const bf16x8*>(
            Vsm + h * 64 + ((((e2 >> 3) ^ (h & 7))) << 3));
        acc_o[hf] = mfma16(pa, vb, acc_o[hf]);
      }
    }
  }
  #pragma unroll
  for (int hf = 0; hf < 8; hf++)
    #pragma unroll
    for (int j = 0; j < 4; j++) {
      int t = qt * 64 + w * 16 + lk * 4 + j;
      float val = acc_o[hf][j] / den[j];
      attn_o[((size_t)(b * TT + t)) * (NHQ * HDM) + n * HDM + hf * 16 + lr] = f2bf(val);
    }
}

// ---------------------------------------------------------------------------
extern "C" void kernel_launch(void* const* d_in, const int* in_sizes, int n_in,
                              void* d_out, int out_size, void* d_ws,
                              size_t ws_size, hipStream_t stream) {
  const float* x_img = (const float*)d_in[0];
  const float* x_txt = (const float*)d_in[1];
  const float* sc_attn_i = (const float*)d_in[3];
  const float* wq_i = (const float*)d_in[4];
  const float* wk_i = (const float*)d_in[5];
  const float* wv_i = (const float*)d_in[6];
  const float* wo_i = (const float*)d_in[7];
  const float* sc_ffw_i = (const float*)d_in[8];
  const float* wg_i = (const float*)d_in[9];
  const float* wu_i = (const float*)d_in[10];
  const float* wd_i = (const float*)d_in[11];
  const float* sc_attn_t = (const float*)d_in[12];
  const float* wq_t = (const float*)d_in[13];
  const float* wk_t = (const float*)d_in[14];
  const float* wv_t = (const float*)d_in[15];
  const float* wo_t = (const float*)d_in[16];
  const float* sc_ffw_t = (const float*)d_in[17];
  const float* wg_t = (const float*)d_in[18];
  const float* wu_t = (const float*)d_in[19];
  const float* wd_t = (const float*)d_in[20];
  float* outp = (float*)d_out;
  float* outp_t = outp + (size_t)2 * 1024 * 2048;

  char* ws = (char*)d_ws;
  size_t off = 0;
  auto alloc = [&](size_t n) {
    char* p = ws + off;
    off += (n + 255) & ~(size_t)255;
    return p;
  };
  bf16* WqT_i = (bf16*)alloc((size_t)2048 * 2048 * 2);
  bf16* WkT_i = (bf16*)alloc((size_t)1024 * 2048 * 2);
  bf16* WvT_i = (bf16*)alloc((size_t)1024 * 2048 * 2);
  bf16* WoT_i = (bf16*)alloc((size_t)2048 * 2048 * 2);
  bf16* WguT_i = (bf16*)alloc((size_t)16384 * 2048 * 2);
  bf16* WdT_i = (bf16*)alloc((size_t)2048 * 8192 * 2);
  bf16* WqT_t = (bf16*)alloc((size_t)2048 * 1024 * 2);
  bf16* WkT_t = (bf16*)alloc((size_t)1024 * 1024 * 2);
  bf16* WvT_t = (bf16*)alloc((size_t)1024 * 1024 * 2);
  bf16* WoT_t = (bf16*)alloc((size_t)1024 * 2048 * 2);
  bf16* WguT_t = (bf16*)alloc((size_t)8192 * 1024 * 2);
  bf16* WdT_t = (bf16*)alloc((size_t)1024 * 4096 * 2);
  bf16* xn_i = (bf16*)alloc((size_t)2048 * 2048 * 2);   // 8 MB
  bf16* xn_t = (bf16*)alloc((size_t)1024 * 1024 * 2);   // 2 MB
  float* h_i = (float*)alloc((size_t)2048 * 2048 * 4);  // 16 MB
  float* h_t = (float*)alloc((size_t)1024 * 1024 * 4);  // 4 MB
  char* S = (char*)alloc((size_t)84 * 1024 * 1024);
  (void)ws_size;
  // phase A (attention) layout in S
  bf16* q_all = (bf16*)S;
  bf16* k_all = (bf16*)(S + 12582912);
  bf16* v_all = (bf16*)(S + 18874368);
  bf16* vtr   = (bf16*)(S + 25165824);
  bf16* attn_o= (bf16*)(S + 31457280);
  // wo split-K partials: over dead q/k/v region (q,k dead after attn; v after transpose)
  float* p1wo_i = (float*)S;                 // 16 MB
  float* p1wo_t = (float*)(S + 16777216);    // 4 MB
  // phase B (FFN) layout in S
  bf16* gu_i  = (bf16*)S;
  bf16* gu_t  = (bf16*)(S + (size_t)2048 * 16384 * 2);
  // down split-K partials: over dead xn/h region (xn dead after gateup, h after rmsnorm)
  float* p1dn_i = (float*)xn_i;                       // 16 MB
  float* p1dn_t = (float*)((char*)xn_i + 16777216);   // 4 MB

  (void)hipFuncSetAttribute(reinterpret_cast<const void*>(gemm8),
                            hipFuncAttributeMaxDynamicSharedMemorySize, 131072);

  // 1. weight transpose/convert
  TJobs tj;
  auto setj = [&](int idx, const float* s, bf16* d, int K, int N) {
    tj.j[idx].src = s; tj.j[idx].dst = d; tj.j[idx].K = K; tj.j[idx].N = N;
  };
  setj(0, wq_i, WqT_i, 2048, 2048);
  setj(1, wk_i, WkT_i, 2048, 1024);
  setj(2, wv_i, WvT_i, 2048, 1024);
  setj(3, wo_i, WoT_i, 2048, 2048);
  setj(4, wg_i, WguT_i, 2048, 8192);
  setj(5, wu_i, WguT_i + (size_t)8192 * 2048, 2048, 8192);
  setj(6, wd_i, WdT_i, 8192, 2048);
  setj(7, wq_t, WqT_t, 1024, 2048);
  setj(8, wk_t, WkT_t, 1024, 1024);
  setj(9, wv_t, WvT_t, 1024, 1024);
  setj(10, wo_t, WoT_t, 2048, 1024);
  setj(11, wg_t, WguT_t, 1024, 4096);
  setj(12, wu_t, WguT_t + (size_t)4096 * 1024, 1024, 4096);
  setj(13, wd_t, WdT_t, 4096, 1024);
  tj.cum[0] = 0;
  for (int i = 0; i < 14; i++)
    tj.cum[i + 1] = tj.cum[i] + (tj.j[i].K >> 6) * (tj.j[i].N >> 6);
  wt_transpose<<<tj.cum[14], 256, 0, stream>>>(tj);

  // 2. pre-attn RMSNorm
  rmsnorm_k<2><<<2048, 256, 0, stream>>>(x_img, sc_attn_i, xn_i);
  rmsnorm_k<1><<<1024, 256, 0, stream>>>(x_txt, sc_attn_t, xn_t);

  // job builders
  auto mk8b = [](const bf16* A, const bf16* B, bf16* Cb, int K, int N, int lda,
                 int ldb, int ab, int ash, int ask, int cb2, int csh, int csk,
                 int cstr) {
    G8Job g{};
    g.A = A; g.B = B; g.Cb = Cb; g.Cf = nullptr;
    g.K = K; g.N = N; g.lda = lda; g.ldb = ldb;
    g.a_base = ab; g.a_lsh = ash; g.a_lskip = ask;
    g.c_base = cb2; g.c_lsh = csh; g.c_lskip = csk; g.c_stride = cstr;
    return g;
  };
  auto mk8f = [](const bf16* A, const bf16* B, float* Cf, int K, int N, int lda,
                 int ldb, int ab, int ash, int ask, int cstr) {
    G8Job g{};
    g.A = A; g.B = B; g.Cb = nullptr; g.Cf = Cf;
    g.K = K; g.N = N; g.lda = lda; g.ldb = ldb;
    g.a_base = ab; g.a_lsh = ash; g.a_lskip = ask;
    g.c_base = 0; g.c_lsh = 30; g.c_lskip = 0; g.c_stride = cstr;
    return g;
  };
  auto launch8 = [&](G8Jobs& P, int nj, const int* Mt) {
    P.nj = nj;
    P.cum[0] = 0;
    for (int i = 0; i < nj; i++) P.cum[i + 1] = P.cum[i] + Mt[i] * (P.j[i].N >> 8);
    gemm8<<<P.cum[nj], 512, 131072, stream>>>(P);
  };

  // 3. QKV via gemm8
  {
    G8Jobs P;
    P.j[0] = mk8b(xn_i, WqT_i, q_all, 2048, 2048, 2048, 2048, 0, 30, 0, 0, 10, 512, 2048);
    P.j[1] = mk8b(xn_i, WkT_i, k_all, 2048, 1024, 2048, 2048, 0, 30, 0, 0, 10, 512, 1024);
    P.j[2] = mk8b(xn_i, WvT_i, v_all, 2048, 1024, 2048, 2048, 0, 30, 0, 0, 10, 512, 1024);
    P.j[3] = mk8b(xn_t, WqT_t, q_all, 1024, 2048, 1024, 1024, 0, 30, 0, 1024, 9, 1024, 2048);
    P.j[4] = mk8b(xn_t, WkT_t, k_all, 1024, 1024, 1024, 1024, 0, 30, 0, 1024, 9, 1024, 1024);
    P.j[5] = mk8b(xn_t, WvT_t, v_all, 1024, 1024, 1024, 1024, 0, 30, 0, 1024, 9, 1024, 1024);
    int Mt[6] = {8, 8, 8, 4, 4, 4};
    launch8(P, 6, Mt);
  }

  // 4. RoPE
  rope_inplace<<<12288, 256, 0, stream>>>(q_all, 4, 0.08838834764831845f);
  rope_inplace<<<6144, 256, 0, stream>>>(k_all, 3, 1.0f);

  // 5. V transpose
  transpose_v<<<dim3(24, 2, 16), 256, 0, stream>>>(v_all, vtr);

  // 6. attention
  attn_k<<<dim3(24, 16, 2), 256, 0, stream>>>(q_all, k_all, vtr, attn_o);

  // 7. WO via gemm8 split-K=2: p0 -> h, p1 -> p1wo; then h += p1 + x
  {
    G8Jobs P;
    P.j[0] = mk8f(attn_o,        WoT_i,        h_i,    1024, 2048, 2048, 2048, 0, 10, 512, 2048);
    P.j[1] = mk8f(attn_o + 1024, WoT_i + 1024, p1wo_i, 1024, 2048, 2048, 2048, 0, 10, 512, 2048);
    P.j[2] = mk8f(attn_o,        WoT_t,        h_t,    1024, 1024, 2048, 2048, 1024, 9, 1024, 1024);
    P.j[3] = mk8f(attn_o + 1024, WoT_t + 1024, p1wo_t, 1024, 1024, 2048, 2048, 1024, 9, 1024, 1024);
    int Mt[4] = {8, 8, 4, 4};
    launch8(P, 4, Mt);
    reduce_add<<<2048, 256, 0, stream>>>(h_i, p1wo_i, x_img, 2048 * 2048 / 4,
                                         h_t, p1wo_t, x_txt, 1024 * 1024 / 4);
  }

  // 8. pre-FFW RMSNorm
  rmsnorm_k<2><<<2048, 256, 0, stream>>>(h_i, sc_ffw_i, xn_i);
  rmsnorm_k<1><<<1024, 256, 0, stream>>>(h_t, sc_ffw_t, xn_t);

  // 9. gate|up via gemm8 -> gu (bf16), then in-place GELU*mul
  {
    G8Jobs P;
    P.j[0] = mk8b(xn_i, WguT_i, gu_i, 2048, 16384, 2048, 2048, 0, 30, 0, 0, 30, 0, 16384);
    P.j[1] = mk8b(xn_t, WguT_t, gu_t, 1024, 8192, 1024, 1024, 0, 30, 0, 0, 30, 0, 8192);
    int Mt[2] = {8, 4};
    launch8(P, 2, Mt);
  }
  {
    int total = 2048 * 8192 / 8 + 1024 * 4096 / 8;
    gelu_mul<<<(total + 255) / 256, 256, 0, stream>>>(gu_i, gu_t);
  }

  // 10. DOWN via gemm8 split-K=2: p0 -> d_out, p1 -> p1dn; then out += p1 + x
  {
    G8Jobs P;
    P.j[0] = mk8f(gu_i,        WdT_i,        outp,   4096, 2048, 16384, 8192, 0, 30, 0, 2048);
    P.j[1] = mk8f(gu_i + 4096, WdT_i + 4096, p1dn_i, 4096, 2048, 16384, 8192, 0, 30, 0, 2048);
    P.j[2] = mk8f(gu_t,        WdT_t,        outp_t, 2048, 1024, 8192,  4096, 0, 30, 0, 1024);
    P.j[3] = mk8f(gu_t + 2048, WdT_t + 2048, p1dn_t, 2048, 1024, 8192,  4096, 0, 30, 0, 1024);
    int Mt[4] = {8, 8, 4, 4};
    launch8(P, 4, Mt);
    reduce_add<<<2048, 256, 0, stream>>>(outp, p1dn_i, x_img, 2048 * 2048 / 4,
                                         outp_t, p1dn_t, x_txt, 1024 * 1024 / 4);
  }
}